// Round 4
// baseline (486.743 us; speedup 1.0000x reference)
//
#include <hip/hip_runtime.h>
#include <hip/hip_bf16.h>

typedef unsigned short u16;
typedef unsigned int u32;
typedef float f32x4 __attribute__((ext_vector_type(4)));
typedef short s16x8 __attribute__((ext_vector_type(8)));

#define MFMA16(a, b, c) __builtin_amdgcn_mfma_f32_16x16x32_bf16(a, b, c, 0, 0, 0)

#define NN 4096
#define CC 256
#define CQ 64

__device__ __forceinline__ u16 f2bf(float x) {
    union { float f; u32 u; } v; v.f = x;
    return (u16)((v.u + 0x7FFFu + ((v.u >> 16) & 1u)) >> 16);
}
__device__ __forceinline__ float bf2f(u16 u) {
    union { u32 u; float f; } v; v.u = ((u32)u) << 16;
    return v.f;
}
// async global->LDS, 16B/lane; dst = wave-uniform base + lane*16 (m104)
__device__ __forceinline__ void gll16(const void* g, void* l) {
    __builtin_amdgcn_global_load_lds(
        (const __attribute__((address_space(1))) void*)g,
        (__attribute__((address_space(3))) void*)l, 16, 0, 0);
}

// ---------------------------------------------------------------------------
// prep: blocks 0..1023: x[b][c][n] f32 -> xT[b][n][c] bf16 (LDS transpose)
//       blocks 1024..1119: Wq|Wk|Wv f32 -> wbf[384][256] bf16
//       block 1120: zero the 256 pair-completion flags (re-done every replay)
// ---------------------------------------------------------------------------
__global__ __launch_bounds__(256) void prep(
    const float* __restrict__ x, const float* __restrict__ Wq,
    const float* __restrict__ Wk, const float* __restrict__ Wv,
    u16* __restrict__ xT, u16* __restrict__ wbf, int* __restrict__ flags)
{
    const int bid = blockIdx.x, t = threadIdx.x;
    if (bid < 1024) {
        __shared__ float tile[64 * 65];
        const int b = bid >> 8, ctile = (bid >> 6) & 3, ntile = bid & 63;
        const int c0 = ctile * 64, n0 = ntile * 64;
        const int cw = t >> 4, nj = (t & 15) * 4;
        for (int it = 0; it < 4; it++) {
            const int ci = it * 16 + cw;
            const float4 v4 = *(const float4*)(x + ((size_t)(b * CC + c0 + ci)) * NN + n0 + nj);
            tile[(nj + 0) * 65 + ci] = v4.x;
            tile[(nj + 1) * 65 + ci] = v4.y;
            tile[(nj + 2) * 65 + ci] = v4.z;
            tile[(nj + 3) * 65 + ci] = v4.w;
        }
        __syncthreads();
        const int r = t >> 2, c16 = (t & 3) * 16;
        union { u16 h[16]; uint4 q[2]; } pk;
        for (int j = 0; j < 16; j++) pk.h[j] = f2bf(tile[r * 65 + c16 + j]);
        u16* dst = xT + ((size_t)(b * NN + n0 + r)) * CC + c0 + c16;
        *(uint4*)dst = pk.q[0];
        *(uint4*)(dst + 8) = pk.q[1];
    } else if (bid < 1120) {
        const int flat = (bid - 1024) * 1024 + t * 4;
        const int o = flat >> 8, c = flat & 255;
        const float* src = (o < 64)  ? (Wq + (size_t)o * CC + c)
                         : (o < 128) ? (Wk + (size_t)(o - 64) * CC + c)
                                     : (Wv + (size_t)(o - 128) * CC + c);
        const float4 v4 = *(const float4*)src;
        union { u16 h[4]; uint2 d; } pk;
        pk.h[0] = f2bf(v4.x); pk.h[1] = f2bf(v4.y);
        pk.h[2] = f2bf(v4.z); pk.h[3] = f2bf(v4.w);
        *(uint2*)(wbf + (size_t)o * CC + c) = pk.d;
    } else {
        flags[t] = 0;      // 256 flags, one per (b, n-tile) pair
    }
}

// ---------------------------------------------------------------------------
// qkv v2: 512 blocks (2/CU) x 512 thr (8 waves; 16 waves/CU). n-tile 32.
// Each wave: 48 W-rows (3 o-tiles) x 32 n. Async swizzled staging.
// ---------------------------------------------------------------------------
__global__ __launch_bounds__(512, 4) void qkv(
    const u16* __restrict__ xT, const u16* __restrict__ wbf,
    const float* __restrict__ bq, const float* __restrict__ bk,
    const float* __restrict__ bv,
    u16* __restrict__ qT, u16* __restrict__ kT, u16* __restrict__ v)
{
    __shared__ __align__(16) u16 sm[384 * 64 + 32 * 64];  // 53248 B
    u16* Ws = sm;             // [384][64] swizzled
    u16* Xs = sm + 384 * 64;  // [32][64] swizzled

    const int bid = blockIdx.x;
    const int b = bid >> 7, n0 = (bid & 127) * 32;
    const int t = threadIdx.x, lane = t & 63, w = t >> 6;
    const int col = lane & 15, quad = lane >> 4;

    f32x4 acc[3][2];
    for (int i = 0; i < 3; i++) { acc[i][0] = f32x4{0,0,0,0}; acc[i][1] = f32x4{0,0,0,0}; }

    for (int cc = 0; cc < 4; cc++) {
        const int c0 = cc * 64;
        for (int m = 0; m < 6; m++) {
            const int g = m * 512 + t;
            const int row = g >> 3, ch = g & 7;
            gll16(wbf + (size_t)row * CC + c0 + ((ch ^ (row & 7)) * 8), Ws + g * 8);
        }
        if (w < 4) {
            const int g = w * 64 + lane;
            const int n = g >> 3, ch = g & 7;
            gll16(xT + ((size_t)(b * NN + n0 + n)) * CC + c0 + ((ch ^ (n & 7)) * 8),
                  Xs + g * 8);
        }
        __syncthreads();
        for (int kk = 0; kk < 2; kk++) {
            s16x8 bx[2];
            for (int nt2 = 0; nt2 < 2; nt2++) {
                const int n = nt2 * 16 + col;
                bx[nt2] = *(const s16x8*)&Xs[n * 64 + (((kk * 4 + quad) ^ (n & 7)) * 8)];
            }
            for (int ot = 0; ot < 3; ot++) {
                const int row = w * 48 + ot * 16 + col;
                const s16x8 a = *(const s16x8*)&Ws[row * 64 + (((kk * 4 + quad) ^ (row & 7)) * 8)];
                acc[ot][0] = MFMA16(a, bx[0], acc[ot][0]);
                acc[ot][1] = MFMA16(a, bx[1], acc[ot][1]);
            }
        }
        __syncthreads();
    }
    for (int ot = 0; ot < 3; ot++) {
        const int og = w * 48 + ot * 16 + quad * 4;   // wave-uniform 16-aligned region
        for (int nt2 = 0; nt2 < 2; nt2++) {
            const int n = n0 + nt2 * 16 + col;
            if (og < 64) {
                union { u16 h[4]; uint2 d; } pk;
                for (int r = 0; r < 4; r++) pk.h[r] = f2bf(acc[ot][nt2][r] + bq[og + r]);
                *(uint2*)(qT + ((size_t)(b * NN + n)) * CQ + og) = pk.d;
            } else if (og < 128) {
                union { u16 h[4]; uint2 d; } pk;
                for (int r = 0; r < 4; r++) pk.h[r] = f2bf(acc[ot][nt2][r] + bk[og - 64 + r]);
                *(uint2*)(kT + ((size_t)(b * NN + n)) * CQ + (og - 64)) = pk.d;
            } else {
                for (int r = 0; r < 4; r++)
                    v[((size_t)(b * CC + og - 128 + r)) * NN + n] =
                        f2bf(acc[ot][nt2][r] + bv[og - 128 + r]);
            }
        }
    }
}

// ---------------------------------------------------------------------------
// flash_attn v8: v5 schedule (best measured: 80.8us) + fused last-finisher
// combine. Each (b, n-tile) has two blocks (jh=0 bf16 partial -> Op0,
// jh=1 f32 partial -> out). After the epilogue each block: threadfence
// (release), atomicAdd ticket; the SECOND finisher threadfence (acquire)
// and performs out = x + g*(O0+O1)/(l0+l1) for its 256c x 64n slice —
// overlapped under still-running flash blocks instead of a serial pass.
// Cross-XCD visibility: device-scope atomic + __threadfence (G12/G16).
// LDS u16: K0@0 K1@2048 | V0@4096 V1@12288 | P0@20480 P1@22528 = 49152 B.
// ---------------------------------------------------------------------------
__global__ __launch_bounds__(512, 4) void flash_attn(
    const u16* __restrict__ qT, const u16* __restrict__ kT,
    const u16* __restrict__ v,
    u16* __restrict__ Op0, float* __restrict__ Op1,
    float* __restrict__ lws,
    const float* __restrict__ x, const float* __restrict__ gamma,
    int* __restrict__ flags)
{
    __shared__ __align__(16) u16 sm[24576];   // 49152 B
    __shared__ float ls[2][64];
    __shared__ int lastFlag;

    const int bid = blockIdx.x;
    const int p = bid & 7;                 // XCD pin: (b, jh) per XCD, K/V-half in L2
    const int b = p >> 1, jh = p & 1;
    const int n0 = (bid >> 3) * 64;
    const int jb = jh * 2048;
    const int t = threadIdx.x;
    const int lane = t & 63, wv = t >> 6;
    const int col = lane & 15, quad = lane >> 4;
    const int strip = wv & 3, jhi = wv >> 2;   // S-phase identity
    const int ih = wv >> 2, cq = wv & 3;       // PV-phase identity

    // per-lane read swizzle for V and P (rows are base+col, base%16==0)
    const int swz8 = (quad ^ ((col >> 1) & 3)) * 8;

    // Q A-frags for S (A[m=i]: row = n0 + strip*16 + col)
    s16x8 aq[2];
    {
        const u16* qp = qT + ((size_t)(b * NN + n0 + strip * 16 + col)) * CQ + quad * 8;
        aq[0] = *(const s16x8*)qp;
        aq[1] = *(const s16x8*)(qp + 32);
    }

    f32x4 o_[2][4];    // D[m=i (quad*4+r), n=c (col)]: [it2 strip][ct c-tile]
    for (int i = 0; i < 2; i++) for (int j = 0; j < 4; j++) o_[i][j] = f32x4{0,0,0,0};
    float lac[4] = {0.f, 0.f, 0.f, 0.f};

    // staging addresses (K: 256 chunks via waves 0-3; V: 1024 chunks, 2/thread)
    const int kg = wv * 64 + lane;             // valid for wv<4
    const int krow = kg >> 3;
    const u16* ksrc = kT + ((size_t)(b * NN + jb + krow)) * CQ + (((kg & 7) ^ (krow & 7)) * 8);
    const int kdo = kg * 8;
    const u16* vsrc[2];
    int vdo[2];
    for (int m = 0; m < 2; m++) {
        const int g = m * 512 + t;
        const int row = g >> 2;                // 4 chunks per 32-j row
        vdo[m] = g * 8;
        // pre-swizzled global source: LDS slot (row, ch) holds global chunk
        // ch ^ ((row>>1)&3); involution matches the read-side XOR.
        vsrc[m] = v + ((size_t)(b * CC + row)) * NN + jb
                    + (((g & 3) ^ ((row >> 1) & 3)) * 8);
    }

    auto issueK = [&](int jt, int kb) {
        if (wv < 4) gll16(ksrc + (size_t)jt * 32 * CQ, sm + kb * 2048 + kdo);
    };
    auto issueV = [&](int jt, int vb) {
        u16* base = sm + 4096 + vb * 8192;
        for (int m = 0; m < 2; m++)
            gll16(vsrc[m] + jt * 32, base + vdo[m]);
    };
    auto S_phase = [&](int kb, int pb) {
        const u16* Kb = sm + kb * 2048;
        u16* Pb = sm + 20480 + pb * 2048;
        f32x4 s = f32x4{0,0,0,0};
        for (int kk = 0; kk < 2; kk++) {
            const int jrow = jhi * 16 + col;
            const s16x8 bk_ = *(const s16x8*)
                &Kb[jrow * 64 + (((kk * 4 + quad) ^ (jrow & 7)) * 8)];
            s = MFMA16(aq[kk], bk_, s);
        }
        const int jch = jhi * 2 + (col >> 3);  // 16B chunk of this lane's j
        const int jin = col & 7;
        for (int r = 0; r < 4; r++) {
            const float pv = __expf(fminf(s[r], 60.f));
            lac[r] += pv;
            const int rrow = strip * 16 + quad * 4 + r;
            Pb[rrow * 32 + ((jch ^ ((quad * 2 + (r >> 1)) & 3)) * 8) + jin] = f2bf(pv);
        }
    };
    auto PV_phase = [&](int pb, int vb) {
        const u16* Pb = sm + 20480 + pb * 2048;
        const u16* Vb = sm + 4096 + vb * 8192;
        s16x8 pa[2];
        for (int it2 = 0; it2 < 2; it2++)
            pa[it2] = *(const s16x8*)&Pb[((ih * 2 + it2) * 16 + col) * 32 + swz8];
        for (int ct = 0; ct < 4; ct++) {
            const int c = cq * 64 + ct * 16 + col;
            const s16x8 bv_ = *(const s16x8*)&Vb[c * 32 + swz8];
            o_[0][ct] = MFMA16(pa[0], bv_, o_[0][ct]);
            o_[1][ct] = MFMA16(pa[1], bv_, o_[1][ct]);
        }
    };

    // skewed 1-barrier pipeline (v2 schedule at half tile)
    issueK(0, 0);
    issueV(0, 0);
    issueK(1, 1);
    __syncthreads();
    S_phase(0, 0);

    int vcur = 0, pcur = 0;
    for (int m = 0; m < 64; m++) {
        __syncthreads();      // drains prior-iter DMAs; P[pcur] visible
        issueV((m + 1 < 64) ? m + 1 : 63, vcur ^ 1);
        issueK((m + 2 < 64) ? m + 2 : 63, m & 1);
        PV_phase(pcur, vcur);
        if (m < 63) S_phase((m + 1) & 1, pcur ^ 1);
        vcur ^= 1; pcur ^= 1;
    }

    // ---- l: reduce over this wave's 16 j-cols, publish per jhi half
    for (int r = 0; r < 4; r++) {
        float lv = lac[r];
        lv += __shfl_xor(lv, 1, 64);
        lv += __shfl_xor(lv, 2, 64);
        lv += __shfl_xor(lv, 4, 64);
        lv += __shfl_xor(lv, 8, 64);
        lac[r] = lv;
    }
    if (col == 0)
        for (int r = 0; r < 4; r++)
            ls[jhi][strip * 16 + quad * 4 + r] = lac[r];
    __syncthreads();   // drains trailing DMAs before sm reuse; ls visible
    if (t < 64)
        lws[(size_t)jh * 4 * NN + (size_t)b * NN + n0 + t] = ls[0][t] + ls[1][t];

    // ---- epilogue: transpose O through LDS in 2 rounds of 128 c
    float* Tf = (float*)sm;    // [128][68] f32 (34.8KB)
    u16*  Tu = sm;             // [128][136] u16
    for (int rd = 0; rd < 2; rd++) {
        if ((cq >> 1) == rd) {
            const int cl = (cq & 1) * 64;
            for (int it2 = 0; it2 < 2; it2++) {
                const int ib = (ih * 2 + it2) * 16 + quad * 4;
                for (int ct = 0; ct < 4; ct++) {
                    const int c = cl + ct * 16 + col;
                    if (jh == 0) {
                        union { u16 h[4]; uint2 d; } pk;
                        for (int r = 0; r < 4; r++) pk.h[r] = f2bf(o_[it2][ct][r]);
                        *(uint2*)&Tu[c * 136 + ib] = pk.d;
                    } else {
                        *(float2*)&Tf[c * 68 + ib] = float2{o_[it2][ct][0], o_[it2][ct][1]};
                        *(float2*)&Tf[c * 68 + ib + 2] = float2{o_[it2][ct][2], o_[it2][ct][3]};
                    }
                }
            }
        }
        __syncthreads();
        const int cl = t >> 2, i0 = (t & 3) * 16;
        const int c = rd * 128 + cl;
        if (jh == 0) {
            u16* dst = Op0 + ((size_t)(b * CC + c)) * NN + n0 + i0;
            *(uint4*)dst       = *(const uint4*)&Tu[cl * 136 + i0];
            *(uint4*)(dst + 8) = *(const uint4*)&Tu[cl * 136 + i0 + 8];
        } else {
            float* dst = Op1 + ((size_t)(b * CC + c)) * NN + n0 + i0;
            for (int k = 0; k < 4; k++)
                *(float4*)(dst + k * 4) = *(const float4*)&Tf[cl * 68 + i0 + k * 4];
        }
        __syncthreads();
    }

    // ---- fused combine: last finisher of the (b, n-tile) pair does the fixup
    __threadfence();                       // release: partials + l visible
    if (t == 0)
        lastFlag = atomicAdd(&flags[(b << 6) + (bid >> 3)], 1);
    __syncthreads();
    if (lastFlag == 1) {
        __threadfence();                   // acquire: partner's writes visible
        const float g = gamma[0];
        const int c = t >> 1;
        const int no = n0 + (t & 1) * 32;
        const size_t rowo = ((size_t)(b * CC + c)) * NN;
        const float* l0p = lws + (size_t)b * NN;
        const float* l1p = lws + (size_t)4 * NN + (size_t)b * NN;
        for (int k = 0; k < 8; k++) {
            const int n = no + k * 4;
            const float4 xv = *(const float4*)(x + rowo + n);
            const float4 o1 = *(const float4*)(Op1 + rowo + n);
            union { uint2 d; u16 h[4]; } o0;
            o0.d = *(const uint2*)(Op0 + rowo + n);
            const float4 l0 = *(const float4*)(l0p + n);
            const float4 l1 = *(const float4*)(l1p + n);
            float4 r;
            r.x = xv.x + g * (bf2f(o0.h[0]) + o1.x) / (l0.x + l1.x);
            r.y = xv.y + g * (bf2f(o0.h[1]) + o1.y) / (l0.y + l1.y);
            r.z = xv.z + g * (bf2f(o0.h[2]) + o1.z) / (l0.z + l1.z);
            r.w = xv.w + g * (bf2f(o0.h[3]) + o1.w) / (l0.w + l1.w);
            *(float4*)(Op1 + rowo + n) = r;
        }
    }
}

// ---------------------------------------------------------------------------
extern "C" void kernel_launch(void* const* d_in, const int* in_sizes, int n_in,
                              void* d_out, int out_size, void* d_ws, size_t ws_size,
                              hipStream_t stream)
{
    const float* x     = (const float*)d_in[0];
    const float* Wq    = (const float*)d_in[1];
    const float* bq    = (const float*)d_in[2];
    const float* Wk    = (const float*)d_in[3];
    const float* bk    = (const float*)d_in[4];
    const float* Wv    = (const float*)d_in[5];
    const float* bv    = (const float*)d_in[6];
    const float* gamma = (const float*)d_in[7];
    float* out = (float*)d_out;

    // ws (u16): xT 8.4MB (reused as Op0) | wbf 196KB (reused as lws 128KB)
    //           | qT 2.1MB | kT 2.1MB | v 8.4MB | flags 1KB  — ~21.2MB
    //           (R2 confirmed ws >= 38MB, so headroom is ample)
    u16* xT  = (u16*)d_ws;
    u16* wbf = xT  + (size_t)4 * NN * CC;
    u16* qTw = wbf + (size_t)384 * CC;
    u16* kTw = qTw + (size_t)4 * NN * CQ;
    u16* vw  = kTw + (size_t)4 * NN * CQ;
    int* flags = (int*)(vw + (size_t)4 * NN * CC);
    u16* Op0 = xT;                 // xT dead after qkv
    float* lws = (float*)wbf;      // wbf dead after qkv

    prep<<<1121, 256, 0, stream>>>(x, Wq, Wk, Wv, xT, wbf, flags);
    qkv<<<512, 512, 0, stream>>>(xT, wbf, bq, bk, bv, qTw, kTw, vw);
    flash_attn<<<512, 512, 0, stream>>>(qTw, kTw, vw, Op0, out, lws,
                                        x, gamma, flags);
}

// Round 6
// 201.997 us; speedup vs baseline: 2.4097x; 2.4097x over previous
//
#include <hip/hip_runtime.h>
#include <hip/hip_bf16.h>

typedef unsigned short u16;
typedef unsigned int u32;
typedef float f32x4 __attribute__((ext_vector_type(4)));
typedef short s16x8 __attribute__((ext_vector_type(8)));

#define MFMA16(a, b, c) __builtin_amdgcn_mfma_f32_16x16x32_bf16(a, b, c, 0, 0, 0)

#define NN 4096
#define CC 256
#define CQ 64

__device__ __forceinline__ u16 f2bf(float x) {
    union { float f; u32 u; } v; v.f = x;
    return (u16)((v.u + 0x7FFFu + ((v.u >> 16) & 1u)) >> 16);
}
__device__ __forceinline__ float bf2f(u16 u) {
    union { u32 u; float f; } v; v.u = ((u32)u) << 16;
    return v.f;
}
// async global->LDS, 16B/lane; dst = wave-uniform base + lane*16 (m104)
__device__ __forceinline__ void gll16(const void* g, void* l) {
    __builtin_amdgcn_global_load_lds(
        (const __attribute__((address_space(1))) void*)g,
        (__attribute__((address_space(3))) void*)l, 16, 0, 0);
}

// ---------------------------------------------------------------------------
// prep: blocks 0..1023: x[b][c][n] f32 -> xT[b][n][c] bf16 (LDS transpose)
//       blocks 1024..1119: Wq|Wk|Wv f32 -> wbf[384][256] bf16
// ---------------------------------------------------------------------------
__global__ __launch_bounds__(256) void prep(
    const float* __restrict__ x, const float* __restrict__ Wq,
    const float* __restrict__ Wk, const float* __restrict__ Wv,
    u16* __restrict__ xT, u16* __restrict__ wbf)
{
    const int bid = blockIdx.x, t = threadIdx.x;
    if (bid < 1024) {
        __shared__ float tile[64 * 65];
        const int b = bid >> 8, ctile = (bid >> 6) & 3, ntile = bid & 63;
        const int c0 = ctile * 64, n0 = ntile * 64;
        const int cw = t >> 4, nj = (t & 15) * 4;
        for (int it = 0; it < 4; it++) {
            const int ci = it * 16 + cw;
            const float4 v4 = *(const float4*)(x + ((size_t)(b * CC + c0 + ci)) * NN + n0 + nj);
            tile[(nj + 0) * 65 + ci] = v4.x;
            tile[(nj + 1) * 65 + ci] = v4.y;
            tile[(nj + 2) * 65 + ci] = v4.z;
            tile[(nj + 3) * 65 + ci] = v4.w;
        }
        __syncthreads();
        const int r = t >> 2, c16 = (t & 3) * 16;
        union { u16 h[16]; uint4 q[2]; } pk;
        for (int j = 0; j < 16; j++) pk.h[j] = f2bf(tile[r * 65 + c16 + j]);
        u16* dst = xT + ((size_t)(b * NN + n0 + r)) * CC + c0 + c16;
        *(uint4*)dst = pk.q[0];
        *(uint4*)(dst + 8) = pk.q[1];
    } else {
        const int flat = (bid - 1024) * 1024 + t * 4;
        const int o = flat >> 8, c = flat & 255;
        const float* src = (o < 64)  ? (Wq + (size_t)o * CC + c)
                         : (o < 128) ? (Wk + (size_t)(o - 64) * CC + c)
                                     : (Wv + (size_t)(o - 128) * CC + c);
        const float4 v4 = *(const float4*)src;
        union { u16 h[4]; uint2 d; } pk;
        pk.h[0] = f2bf(v4.x); pk.h[1] = f2bf(v4.y);
        pk.h[2] = f2bf(v4.z); pk.h[3] = f2bf(v4.w);
        *(uint2*)(wbf + (size_t)o * CC + c) = pk.d;
    }
}

// ---------------------------------------------------------------------------
// qkv v2: 512 blocks (2/CU) x 512 thr (8 waves; 16 waves/CU). n-tile 32.
// Each wave: 48 W-rows (3 o-tiles) x 32 n. Async swizzled staging.
// ---------------------------------------------------------------------------
__global__ __launch_bounds__(512, 4) void qkv(
    const u16* __restrict__ xT, const u16* __restrict__ wbf,
    const float* __restrict__ bq, const float* __restrict__ bk,
    const float* __restrict__ bv,
    u16* __restrict__ qT, u16* __restrict__ kT, u16* __restrict__ v)
{
    __shared__ __align__(16) u16 sm[384 * 64 + 32 * 64];  // 53248 B
    u16* Ws = sm;             // [384][64] swizzled
    u16* Xs = sm + 384 * 64;  // [32][64] swizzled

    const int bid = blockIdx.x;
    const int b = bid >> 7, n0 = (bid & 127) * 32;
    const int t = threadIdx.x, lane = t & 63, w = t >> 6;
    const int col = lane & 15, quad = lane >> 4;

    f32x4 acc[3][2];
    for (int i = 0; i < 3; i++) { acc[i][0] = f32x4{0,0,0,0}; acc[i][1] = f32x4{0,0,0,0}; }

    for (int cc = 0; cc < 4; cc++) {
        const int c0 = cc * 64;
        for (int m = 0; m < 6; m++) {
            const int g = m * 512 + t;
            const int row = g >> 3, ch = g & 7;
            gll16(wbf + (size_t)row * CC + c0 + ((ch ^ (row & 7)) * 8), Ws + g * 8);
        }
        if (w < 4) {
            const int g = w * 64 + lane;
            const int n = g >> 3, ch = g & 7;
            gll16(xT + ((size_t)(b * NN + n0 + n)) * CC + c0 + ((ch ^ (n & 7)) * 8),
                  Xs + g * 8);
        }
        __syncthreads();
        for (int kk = 0; kk < 2; kk++) {
            s16x8 bx[2];
            for (int nt2 = 0; nt2 < 2; nt2++) {
                const int n = nt2 * 16 + col;
                bx[nt2] = *(const s16x8*)&Xs[n * 64 + (((kk * 4 + quad) ^ (n & 7)) * 8)];
            }
            for (int ot = 0; ot < 3; ot++) {
                const int row = w * 48 + ot * 16 + col;
                const s16x8 a = *(const s16x8*)&Ws[row * 64 + (((kk * 4 + quad) ^ (row & 7)) * 8)];
                acc[ot][0] = MFMA16(a, bx[0], acc[ot][0]);
                acc[ot][1] = MFMA16(a, bx[1], acc[ot][1]);
            }
        }
        __syncthreads();
    }
    for (int ot = 0; ot < 3; ot++) {
        const int og = w * 48 + ot * 16 + quad * 4;   // wave-uniform 16-aligned region
        for (int nt2 = 0; nt2 < 2; nt2++) {
            const int n = n0 + nt2 * 16 + col;
            if (og < 64) {
                union { u16 h[4]; uint2 d; } pk;
                for (int r = 0; r < 4; r++) pk.h[r] = f2bf(acc[ot][nt2][r] + bq[og + r]);
                *(uint2*)(qT + ((size_t)(b * NN + n)) * CQ + og) = pk.d;
            } else if (og < 128) {
                union { u16 h[4]; uint2 d; } pk;
                for (int r = 0; r < 4; r++) pk.h[r] = f2bf(acc[ot][nt2][r] + bk[og - 64 + r]);
                *(uint2*)(kT + ((size_t)(b * NN + n)) * CQ + (og - 64)) = pk.d;
            } else {
                for (int r = 0; r < 4; r++)
                    v[((size_t)(b * CC + og - 128 + r)) * NN + n] =
                        f2bf(acc[ot][nt2][r] + bv[og - 128 + r]);
            }
        }
    }
}

// ---------------------------------------------------------------------------
// flash_attn v11: i-split instead of j-split -> NO combine kernel, no
// partials, no cross-block sync. 512 blocks = (b, 128 n-tiles of 32 i).
// Each block: 32 i-rows x ALL 4096 j (128 iters of the proven v5 skewed
// 1-barrier schedule), then writes FINAL out = x + g*O/l for its disjoint
// 256c x 32n slab. Total MFMA identical to v5 (no duplication); per-CU
// rate identical (2 blocks/CU x 40 MFMA/iter = v5's 160 per 64-j window).
// S: waves 0-3 (strip=wv&1 -> 16 i, sjhi=wv>>1 -> 16 j), 2 MFMA each.
// PV: all 8 waves (it=wv>>2 i-tile, cq=wv&3 -> 64 c), 4 MFMA each.
// V/P XOR swizzles and XCD K/V pinning identical to v5 (verified 98K confl).
// LDS u16: K0@0 K1@2048 | V0@4096 V1@12288 | P0@20480 P1@21504 = 45056 B
// -> 2 blocks/CU.
// ---------------------------------------------------------------------------
__global__ __launch_bounds__(512, 4) void flash_attn(
    const u16* __restrict__ qT, const u16* __restrict__ kT,
    const u16* __restrict__ v,
    const float* __restrict__ x, const float* __restrict__ gamma,
    float* __restrict__ out)
{
    __shared__ __align__(16) u16 sm[22528];   // 45056 B
    __shared__ float ls[2][32];
    __shared__ float lf[32];

    const int bid = blockIdx.x;
    const int p = bid & 7;                 // XCD pin: same b -> same XCD pair
    const int b = p >> 1, npar = p & 1;
    const int n0 = ((bid >> 3) * 2 + npar) * 32;
    const int t = threadIdx.x;
    const int lane = t & 63, wv = t >> 6;
    const int col = lane & 15, quad = lane >> 4;
    const int sstrip = wv & 1, sjhi = (wv >> 1) & 1;  // S identity (wv<4)
    const int it = wv >> 2, cq = wv & 3;              // PV identity

    // per-lane read swizzle for V and P (rows are 16-aligned base + col)
    const int swz8 = (quad ^ ((col >> 1) & 3)) * 8;

    // Q A-frags for S (rows n0 + sstrip*16 + col)
    s16x8 aq[2];
    {
        const u16* qp = qT + ((size_t)(b * NN + n0 + sstrip * 16 + col)) * CQ + quad * 8;
        aq[0] = *(const s16x8*)qp;
        aq[1] = *(const s16x8*)(qp + 32);
    }

    f32x4 o_[4];       // PV acc: D[m=i(quad*4+r), n=c(col)] per c-tile ct
    for (int j = 0; j < 4; j++) o_[j] = f32x4{0,0,0,0};
    float lac[4] = {0.f, 0.f, 0.f, 0.f};

    // staging addresses (K: 256 chunks via waves 0-3; V: 1024 chunks, 2/thread)
    const int kg = wv * 64 + lane;             // valid for wv<4
    const int krow = kg >> 3;
    const u16* ksrc = kT + ((size_t)(b * NN + krow)) * CQ + (((kg & 7) ^ (krow & 7)) * 8);
    const int kdo = kg * 8;
    const u16* vsrc[2];
    int vdo[2];
    for (int m = 0; m < 2; m++) {
        const int g = m * 512 + t;
        const int row = g >> 2;                // 4 chunks per 32-j row
        vdo[m] = g * 8;
        // pre-swizzled global source matches the read-side XOR (involution)
        vsrc[m] = v + ((size_t)(b * CC + row)) * NN
                    + (((g & 3) ^ ((row >> 1) & 3)) * 8);
    }

    auto issueK = [&](int jt, int kb) {
        if (wv < 4) gll16(ksrc + (size_t)jt * 32 * CQ, sm + kb * 2048 + kdo);
    };
    auto issueV = [&](int jt, int vb) {
        u16* base = sm + 4096 + vb * 8192;
        for (int m = 0; m < 2; m++)
            gll16(vsrc[m] + jt * 32, base + vdo[m]);
    };
    auto S_phase = [&](int kb, int pb) {
        if (wv < 4) {
            const u16* Kb = sm + kb * 2048;
            u16* Pb = sm + 20480 + pb * 1024;
            f32x4 s = f32x4{0,0,0,0};
            for (int kk = 0; kk < 2; kk++) {
                const int jrow = sjhi * 16 + col;
                const s16x8 bk_ = *(const s16x8*)
                    &Kb[jrow * 64 + (((kk * 4 + quad) ^ (jrow & 7)) * 8)];
                s = MFMA16(aq[kk], bk_, s);
            }
            const int jch = sjhi * 2 + (col >> 3);  // 16B chunk of this lane's j
            const int jin = col & 7;
            for (int r = 0; r < 4; r++) {
                const float pv = __expf(fminf(s[r], 60.f));
                lac[r] += pv;
                const int rrow = sstrip * 16 + quad * 4 + r;
                Pb[rrow * 32 + ((jch ^ ((quad * 2 + (r >> 1)) & 3)) * 8) + jin] = f2bf(pv);
            }
        }
    };
    auto PV_phase = [&](int pb, int vb) {
        const u16* Pb = sm + 20480 + pb * 1024;
        const u16* Vb = sm + 4096 + vb * 8192;
        const s16x8 pa = *(const s16x8*)&Pb[(it * 16 + col) * 32 + swz8];
        for (int ct = 0; ct < 4; ct++) {
            const int c = cq * 64 + ct * 16 + col;
            const s16x8 bv_ = *(const s16x8*)&Vb[c * 32 + swz8];
            o_[ct] = MFMA16(pa, bv_, o_[ct]);
        }
    };

    // skewed 1-barrier pipeline (v5 schedule), 128 iters over all 4096 j
    issueK(0, 0);
    issueV(0, 0);
    issueK(1, 1);
    __syncthreads();
    S_phase(0, 0);

    int vcur = 0, pcur = 0;
    for (int m = 0; m < 128; m++) {
        __syncthreads();      // drains prior-iter DMAs; P[pcur] visible
        issueV((m + 1 < 128) ? m + 1 : 127, vcur ^ 1);
        issueK((m + 2 < 128) ? m + 2 : 127, m & 1);
        PV_phase(pcur, vcur);
        if (m < 127) S_phase((m + 1) & 1, pcur ^ 1);
        vcur ^= 1; pcur ^= 1;
    }

    // ---- l: reduce each S-wave's 16 j-cols, publish per sjhi half
    for (int r = 0; r < 4; r++) {
        float lv = lac[r];
        lv += __shfl_xor(lv, 1, 64);
        lv += __shfl_xor(lv, 2, 64);
        lv += __shfl_xor(lv, 4, 64);
        lv += __shfl_xor(lv, 8, 64);
        lac[r] = lv;
    }
    if (wv < 4 && col == 0)
        for (int r = 0; r < 4; r++)
            ls[sjhi][sstrip * 16 + quad * 4 + r] = lac[r];
    __syncthreads();   // also drains trailing DMAs before sm reuse
    if (t < 32) lf[t] = ls[0][t] + ls[1][t];
    __syncthreads();

    // ---- epilogue: transpose O through LDS, write FINAL out = x + g*O/l
    const float g = gamma[0];
    float* Tf = (float*)sm;    // [64][36] f32 (9.2 KB)
    for (int rd = 0; rd < 4; rd++) {
        if (cq == rd) {
            for (int ct = 0; ct < 4; ct++) {
                const int cl = ct * 16 + col;
                const int ib = it * 16 + quad * 4;
                *(float2*)&Tf[cl * 36 + ib]     = float2{o_[ct][0], o_[ct][1]};
                *(float2*)&Tf[cl * 36 + ib + 2] = float2{o_[ct][2], o_[ct][3]};
            }
        }
        __syncthreads();
        const int cl = t >> 3, i0 = (t & 7) * 4;
        const int c = rd * 64 + cl;
        const size_t rowo = ((size_t)(b * CC + c)) * NN + n0 + i0;
        const float2 oa = *(const float2*)&Tf[cl * 36 + i0];
        const float2 ob = *(const float2*)&Tf[cl * 36 + i0 + 2];
        const float4 xv = *(const float4*)(x + rowo);
        float4 r;
        r.x = xv.x + g * oa.x / lf[i0 + 0];
        r.y = xv.y + g * oa.y / lf[i0 + 1];
        r.z = xv.z + g * ob.x / lf[i0 + 2];
        r.w = xv.w + g * ob.y / lf[i0 + 3];
        *(float4*)(out + rowo) = r;
        __syncthreads();
    }
}

// ---------------------------------------------------------------------------
extern "C" void kernel_launch(void* const* d_in, const int* in_sizes, int n_in,
                              void* d_out, int out_size, void* d_ws, size_t ws_size,
                              hipStream_t stream)
{
    const float* x     = (const float*)d_in[0];
    const float* Wq    = (const float*)d_in[1];
    const float* bq    = (const float*)d_in[2];
    const float* Wk    = (const float*)d_in[3];
    const float* bk    = (const float*)d_in[4];
    const float* Wv    = (const float*)d_in[5];
    const float* bv    = (const float*)d_in[6];
    const float* gamma = (const float*)d_in[7];
    float* out = (float*)d_out;

    // ws (u16): xT 8.4MB | wbf 196KB | qT 2.1MB | kT 2.1MB | v 8.4MB ~ 21.2MB
    u16* xT  = (u16*)d_ws;
    u16* wbf = xT  + (size_t)4 * NN * CC;
    u16* qTw = wbf + (size_t)384 * CC;
    u16* kTw = qTw + (size_t)4 * NN * CQ;
    u16* vw  = kTw + (size_t)4 * NN * CQ;

    prep<<<1120, 256, 0, stream>>>(x, Wq, Wk, Wv, xT, wbf);
    qkv<<<512, 512, 0, stream>>>(xT, wbf, bq, bk, bv, qTw, kTw, vw);
    flash_attn<<<512, 512, 0, stream>>>(qTw, kTw, vw, x, gamma, out);
}

// Round 8
// 184.595 us; speedup vs baseline: 2.6368x; 1.0943x over previous
//
#include <hip/hip_runtime.h>
#include <hip/hip_bf16.h>

typedef unsigned short u16;
typedef unsigned int u32;
typedef float f32x4 __attribute__((ext_vector_type(4)));
typedef short s16x8 __attribute__((ext_vector_type(8)));

#define MFMA16(a, b, c) __builtin_amdgcn_mfma_f32_16x16x32_bf16(a, b, c, 0, 0, 0)

#define NN 4096
#define CC 256
#define CQ 64

__device__ __forceinline__ u16 f2bf(float x) {
    union { float f; u32 u; } v; v.f = x;
    return (u16)((v.u + 0x7FFFu + ((v.u >> 16) & 1u)) >> 16);
}
__device__ __forceinline__ float bf2f(u16 u) {
    union { u32 u; float f; } v; v.u = ((u32)u) << 16;
    return v.f;
}
// async global->LDS, 16B/lane; dst = wave-uniform base + lane*16 (m104)
__device__ __forceinline__ void gll16(const void* g, void* l) {
    __builtin_amdgcn_global_load_lds(
        (const __attribute__((address_space(1))) void*)g,
        (__attribute__((address_space(3))) void*)l, 16, 0, 0);
}

// ---------------------------------------------------------------------------
// prep: blocks 0..1023: x[b][c][n] f32 -> xT[b][n][c] bf16 (LDS transpose)
//       blocks 1024..1119: Wq|Wk|Wv f32 -> wbf[384][256] bf16
// ---------------------------------------------------------------------------
__global__ __launch_bounds__(256) void prep(
    const float* __restrict__ x, const float* __restrict__ Wq,
    const float* __restrict__ Wk, const float* __restrict__ Wv,
    u16* __restrict__ xT, u16* __restrict__ wbf)
{
    const int bid = blockIdx.x, t = threadIdx.x;
    if (bid < 1024) {
        __shared__ float tile[64 * 65];
        const int b = bid >> 8, ctile = (bid >> 6) & 3, ntile = bid & 63;
        const int c0 = ctile * 64, n0 = ntile * 64;
        const int cw = t >> 4, nj = (t & 15) * 4;
        for (int it = 0; it < 4; it++) {
            const int ci = it * 16 + cw;
            const float4 v4 = *(const float4*)(x + ((size_t)(b * CC + c0 + ci)) * NN + n0 + nj);
            tile[(nj + 0) * 65 + ci] = v4.x;
            tile[(nj + 1) * 65 + ci] = v4.y;
            tile[(nj + 2) * 65 + ci] = v4.z;
            tile[(nj + 3) * 65 + ci] = v4.w;
        }
        __syncthreads();
        const int r = t >> 2, c16 = (t & 3) * 16;
        union { u16 h[16]; uint4 q[2]; } pk;
        for (int j = 0; j < 16; j++) pk.h[j] = f2bf(tile[r * 65 + c16 + j]);
        u16* dst = xT + ((size_t)(b * NN + n0 + r)) * CC + c0 + c16;
        *(uint4*)dst = pk.q[0];
        *(uint4*)(dst + 8) = pk.q[1];
    } else {
        const int flat = (bid - 1024) * 1024 + t * 4;
        const int o = flat >> 8, c = flat & 255;
        const float* src = (o < 64)  ? (Wq + (size_t)o * CC + c)
                         : (o < 128) ? (Wk + (size_t)(o - 64) * CC + c)
                                     : (Wv + (size_t)(o - 128) * CC + c);
        const float4 v4 = *(const float4*)src;
        union { u16 h[4]; uint2 d; } pk;
        pk.h[0] = f2bf(v4.x); pk.h[1] = f2bf(v4.y);
        pk.h[2] = f2bf(v4.z); pk.h[3] = f2bf(v4.w);
        *(uint2*)(wbf + (size_t)o * CC + c) = pk.d;
    }
}

// ---------------------------------------------------------------------------
// qkv v2: 512 blocks (2/CU) x 512 thr (8 waves; 16 waves/CU). n-tile 32.
// Each wave: 48 W-rows (3 o-tiles) x 32 n. Async swizzled staging.
// ---------------------------------------------------------------------------
__global__ __launch_bounds__(512, 4) void qkv(
    const u16* __restrict__ xT, const u16* __restrict__ wbf,
    const float* __restrict__ bq, const float* __restrict__ bk,
    const float* __restrict__ bv,
    u16* __restrict__ qT, u16* __restrict__ kT, u16* __restrict__ v)
{
    __shared__ __align__(16) u16 sm[384 * 64 + 32 * 64];  // 53248 B
    u16* Ws = sm;             // [384][64] swizzled
    u16* Xs = sm + 384 * 64;  // [32][64] swizzled

    const int bid = blockIdx.x;
    const int b = bid >> 7, n0 = (bid & 127) * 32;
    const int t = threadIdx.x, lane = t & 63, w = t >> 6;
    const int col = lane & 15, quad = lane >> 4;

    f32x4 acc[3][2];
    for (int i = 0; i < 3; i++) { acc[i][0] = f32x4{0,0,0,0}; acc[i][1] = f32x4{0,0,0,0}; }

    for (int cc = 0; cc < 4; cc++) {
        const int c0 = cc * 64;
        for (int m = 0; m < 6; m++) {
            const int g = m * 512 + t;
            const int row = g >> 3, ch = g & 7;
            gll16(wbf + (size_t)row * CC + c0 + ((ch ^ (row & 7)) * 8), Ws + g * 8);
        }
        if (w < 4) {
            const int g = w * 64 + lane;
            const int n = g >> 3, ch = g & 7;
            gll16(xT + ((size_t)(b * NN + n0 + n)) * CC + c0 + ((ch ^ (n & 7)) * 8),
                  Xs + g * 8);
        }
        __syncthreads();
        for (int kk = 0; kk < 2; kk++) {
            s16x8 bx[2];
            for (int nt2 = 0; nt2 < 2; nt2++) {
                const int n = nt2 * 16 + col;
                bx[nt2] = *(const s16x8*)&Xs[n * 64 + (((kk * 4 + quad) ^ (n & 7)) * 8)];
            }
            for (int ot = 0; ot < 3; ot++) {
                const int row = w * 48 + ot * 16 + col;
                const s16x8 a = *(const s16x8*)&Ws[row * 64 + (((kk * 4 + quad) ^ (row & 7)) * 8)];
                acc[ot][0] = MFMA16(a, bx[0], acc[ot][0]);
                acc[ot][1] = MFMA16(a, bx[1], acc[ot][1]);
            }
        }
        __syncthreads();
    }
    for (int ot = 0; ot < 3; ot++) {
        const int og = w * 48 + ot * 16 + quad * 4;   // wave-uniform 16-aligned region
        for (int nt2 = 0; nt2 < 2; nt2++) {
            const int n = n0 + nt2 * 16 + col;
            if (og < 64) {
                union { u16 h[4]; uint2 d; } pk;
                for (int r = 0; r < 4; r++) pk.h[r] = f2bf(acc[ot][nt2][r] + bq[og + r]);
                *(uint2*)(qT + ((size_t)(b * NN + n)) * CQ + og) = pk.d;
            } else if (og < 128) {
                union { u16 h[4]; uint2 d; } pk;
                for (int r = 0; r < 4; r++) pk.h[r] = f2bf(acc[ot][nt2][r] + bk[og - 64 + r]);
                *(uint2*)(kT + ((size_t)(b * NN + n)) * CQ + (og - 64)) = pk.d;
            } else {
                for (int r = 0; r < 4; r++)
                    v[((size_t)(b * CC + og - 128 + r)) * NN + n] =
                        f2bf(acc[ot][nt2][r] + bv[og - 128 + r]);
            }
        }
    }
}

// ---------------------------------------------------------------------------
// flash_attn v12: swapped-operand S (T12 mechanism) -> P is WAVE-PRIVATE.
// S = mfma(A=K, B=Q): D has n=q=col (lane-local q), m=j=quad*4+r. Each wave
// (qt: 16 q-rows, ch: 128 c-cols) computes S for its own q over all 32 j
// (2x dup across ch), exp + l lane-local, then a wave-private LDS round-trip
// (4 ds_write_b32 + 1 ds_read_b128, chunk-XOR by col&3) converts P from
// D-layout (k=quad*4+r) to A-frag layout (k=quad*8+e) for PV. PV consumes P
// in the SAME iteration -> no cross-wave S->PV dependency; the per-iter
// barrier only rotates K/V dbufs (DMA issued 1 iter ahead, drained at next
// barrier). K-frag A (j=col rows) and V-frag B reads reuse v5's verified
// swizzled layouts; staging DMA identical to v5.
// LDS u16: K 2x2048 @0 | V 2x8192 @4096 | Pw 8x512 @20480 = 49152 B -> 2/CU.
// jh j-split + bf16/f32 partials + cheap combine (measured ~4us) kept.
// ---------------------------------------------------------------------------
__global__ __launch_bounds__(512, 4) void flash_attn(
    const u16* __restrict__ qT, const u16* __restrict__ kT,
    const u16* __restrict__ v,
    u16* __restrict__ Op0, float* __restrict__ Op1,
    float* __restrict__ lws)
{
    __shared__ __align__(16) u16 sm[24576];   // 49152 B
    __shared__ float ls[64];

    const int bid = blockIdx.x;
    const int p = bid & 7;                 // XCD pin: (b, jh) per XCD, K/V-half in L2
    const int b = p >> 1, jh = p & 1;
    const int n0 = (bid >> 3) * 64;
    const int jb = jh * 2048;
    const int t = threadIdx.x;
    const int lane = t & 63, wv = t >> 6;
    const int col = lane & 15, quad = lane >> 4;
    const int qt = wv & 3, ch = wv >> 2;   // wave identity: 16 q-rows, 128 c-cols

    // per-lane read swizzle for V (rows are 16-aligned base + col) — v5-proven
    const int swz8 = (quad ^ ((col >> 1) & 3)) * 8;
    const int cx = col & 3;                // P chunk-XOR key (wave-private tile)

    // Q B-frags: lane provides Q[ck=ckh*32+quad*8+e][q=n0+qt*16+col]
    s16x8 qfrag[2];
    {
        const u16* qp = qT + ((size_t)(b * NN + n0 + qt * 16 + col)) * CQ + quad * 8;
        qfrag[0] = *(const s16x8*)qp;
        qfrag[1] = *(const s16x8*)(qp + 32);
    }

    f32x4 o_[8];       // O acc: D[m=q(quad*4+r)][n=c(col)] per c-tile ct
    for (int j = 0; j < 8; j++) o_[j] = f32x4{0,0,0,0};
    float lac = 0.f;

    // staging addresses (K: 256 chunks via waves 0-3; V: 1024 chunks, 2/thread)
    const int kg = wv * 64 + lane;             // valid for wv<4
    const int krow = kg >> 3;
    const u16* ksrc = kT + ((size_t)(b * NN + jb + krow)) * CQ + (((kg & 7) ^ (krow & 7)) * 8);
    const int kdo = kg * 8;
    const u16* vsrc[2];
    int vdo[2];
    for (int m = 0; m < 2; m++) {
        const int g = m * 512 + t;
        const int row = g >> 2;                // 4 chunks per 32-j row
        vdo[m] = g * 8;
        // pre-swizzled global source matches the read-side XOR (involution)
        vsrc[m] = v + ((size_t)(b * CC + row)) * NN + jb
                    + (((g & 3) ^ ((row >> 1) & 3)) * 8);
    }

    auto issueK = [&](int jt, int kb) {
        if (wv < 4) gll16(ksrc + (size_t)jt * 32 * CQ, sm + kb * 2048 + kdo);
    };
    auto issueV = [&](int jt, int vb) {
        u16* base = sm + 4096 + vb * 8192;
        for (int m = 0; m < 2; m++)
            gll16(vsrc[m] + jt * 32, base + vdo[m]);
    };

    u16* Pw = sm + 20480 + wv * 512;           // wave-private [16][32] u16

    auto compute = [&](int m) {
        const u16* Kb = sm + (m & 1) * 2048;
        const u16* Vb = sm + 4096 + (m & 1) * 8192;
        // ---- S = K · Q  (A=K[j][ck], B=Q[ck][q]) -> lane: q=col, j=quad*4+r
        f32x4 sa0 = f32x4{0,0,0,0}, sa1 = f32x4{0,0,0,0};
        for (int ckh = 0; ckh < 2; ckh++) {
            const int kc = (((ckh * 4 + quad) ^ (col & 7)) * 8);
            const s16x8 k0 = *(const s16x8*)&Kb[col * 64 + kc];
            const s16x8 k1 = *(const s16x8*)&Kb[(16 + col) * 64 + kc];
            sa0 = MFMA16(k0, qfrag[ckh], sa0);
            sa1 = MFMA16(k1, qfrag[ckh], sa1);
        }
        // ---- exp + l (lane-local) + pack P pairs
        float p0[4], p1[4];
        for (int r = 0; r < 4; r++) {
            p0[r] = __expf(fminf(sa0[r], 60.f));
            p1[r] = __expf(fminf(sa1[r], 60.f));
            lac += p0[r] + p1[r];
        }
        // ---- wave-private P round-trip: D-layout -> A-frag layout
        // write u32 pair (j, j+1), j = jt*16 + quad*4 + 2i, at chunk
        // (j/8)^cx, u32 slot (quad&1)*2+i; read chunk quad^cx (j=quad*8..+7)
        u32* Pr = (u32*)&Pw[col * 32];
        const int q2 = (quad & 1) << 1;
        Pr[((((quad >> 1)    ) ^ cx) << 2) + q2 + 0] = (u32)f2bf(p0[0]) | ((u32)f2bf(p0[1]) << 16);
        Pr[((((quad >> 1)    ) ^ cx) << 2) + q2 + 1] = (u32)f2bf(p0[2]) | ((u32)f2bf(p0[3]) << 16);
        Pr[(((2 + (quad >> 1)) ^ cx) << 2) + q2 + 0] = (u32)f2bf(p1[0]) | ((u32)f2bf(p1[1]) << 16);
        Pr[(((2 + (quad >> 1)) ^ cx) << 2) + q2 + 1] = (u32)f2bf(p1[2]) | ((u32)f2bf(p1[3]) << 16);
        const s16x8 pa = *(const s16x8*)&Pw[col * 32 + ((quad ^ cx) * 8)];
        // ---- PV: O[q][c] += P[q][j] · V[j][c]
        #pragma unroll
        for (int ct = 0; ct < 8; ct++) {
            const int c = ch * 128 + ct * 16 + col;
            const s16x8 bv_ = *(const s16x8*)&Vb[c * 32 + swz8];
            o_[ct] = MFMA16(pa, bv_, o_[ct]);
        }
    };

    // ---- pipeline: DMA(m+1) issued at iter m, drained at barrier of m+1
    issueK(0, 0);
    issueV(0, 0);
    for (int m = 0; m < 64; m++) {
        __syncthreads();      // K(m),V(m) visible; prior buffers free
        const int jn = (m + 1 < 64) ? m + 1 : 63;
        issueK(jn, (m + 1) & 1);
        issueV(jn, (m + 1) & 1);
        compute(m);
    }

    // ---- l: reduce over quads (lane holds l[q=col] partial for its quad's j)
    lac += __shfl_xor(lac, 16, 64);
    lac += __shfl_xor(lac, 32, 64);
    if (ch == 0 && lane < 16) ls[qt * 16 + lane] = lac;
    __syncthreads();   // drains trailing DMAs before sm reuse; ls visible
    if (t < 64) lws[(size_t)jh * 4 * NN + (size_t)b * NN + n0 + t] = ls[t];

    // ---- epilogue: transpose O through LDS in 2 rounds of 128 c
    float* Tf = (float*)sm;    // [128][68] f32 (34.8KB)
    u16*  Tu = sm;             // [128][136] u16
    for (int rd = 0; rd < 2; rd++) {
        if (ch == rd) {
            const int ib = qt * 16 + quad * 4;
            for (int ct = 0; ct < 8; ct++) {
                const int cl = ct * 16 + col;
                if (jh == 0) {
                    union { u16 h[4]; uint2 d; } pk;
                    for (int r = 0; r < 4; r++) pk.h[r] = f2bf(o_[ct][r]);
                    *(uint2*)&Tu[cl * 136 + ib] = pk.d;
                } else {
                    *(float2*)&Tf[cl * 68 + ib]     = float2{o_[ct][0], o_[ct][1]};
                    *(float2*)&Tf[cl * 68 + ib + 2] = float2{o_[ct][2], o_[ct][3]};
                }
            }
        }
        __syncthreads();
        const int cl = t >> 2, i0 = (t & 3) * 16;
        const int c = rd * 128 + cl;
        if (jh == 0) {
            u16* dst = Op0 + ((size_t)(b * CC + c)) * NN + n0 + i0;
            *(uint4*)dst       = *(const uint4*)&Tu[cl * 136 + i0];
            *(uint4*)(dst + 8) = *(const uint4*)&Tu[cl * 136 + i0 + 8];
        } else {
            float* dst = Op1 + ((size_t)(b * CC + c)) * NN + n0 + i0;
            for (int k = 0; k < 4; k++)
                *(float4*)(dst + k * 4) = *(const float4*)&Tf[cl * 68 + i0 + k * 4];
        }
        __syncthreads();
    }
}

// ---------------------------------------------------------------------------
// combine: out = x + gamma * (O0 + O1) / (l0 + l1)   (in-place over d_out=O1)
// ---------------------------------------------------------------------------
__global__ __launch_bounds__(256) void combine(
    const float* __restrict__ x, const u16* __restrict__ Op0,
    const float* __restrict__ lws, const float* __restrict__ gamma,
    float* __restrict__ out)
{
    const size_t idx = ((size_t)blockIdx.x * 256 + threadIdx.x) * 4;
    const int b = (int)(idx >> 20);
    const int n = (int)(idx & (NN - 1));
    const float g = gamma[0];
    const float4 xv = *(const float4*)(x + idx);
    const float4 o1 = *(const float4*)(out + idx);
    union { uint2 d; u16 h[4]; } o0;
    o0.d = *(const uint2*)(Op0 + idx);
    const float4 l0 = *(const float4*)(lws + (size_t)b * NN + n);
    const float4 l1 = *(const float4*)(lws + (size_t)4 * NN + (size_t)b * NN + n);
    float4 r;
    r.x = xv.x + g * (bf2f(o0.h[0]) + o1.x) / (l0.x + l1.x);
    r.y = xv.y + g * (bf2f(o0.h[1]) + o1.y) / (l0.y + l1.y);
    r.z = xv.z + g * (bf2f(o0.h[2]) + o1.z) / (l0.z + l1.z);
    r.w = xv.w + g * (bf2f(o0.h[3]) + o1.w) / (l0.w + l1.w);
    *(float4*)(out + idx) = r;
}

// ---------------------------------------------------------------------------
extern "C" void kernel_launch(void* const* d_in, const int* in_sizes, int n_in,
                              void* d_out, int out_size, void* d_ws, size_t ws_size,
                              hipStream_t stream)
{
    const float* x     = (const float*)d_in[0];
    const float* Wq    = (const float*)d_in[1];
    const float* bq    = (const float*)d_in[2];
    const float* Wk    = (const float*)d_in[3];
    const float* bk    = (const float*)d_in[4];
    const float* Wv    = (const float*)d_in[5];
    const float* bv    = (const float*)d_in[6];
    const float* gamma = (const float*)d_in[7];
    float* out = (float*)d_out;

    // ws (u16): xT 8.4MB (reused as Op0) | wbf 196KB (reused as lws 128KB)
    //           | qT 2.1MB | kT 2.1MB | v 8.4MB  — total ~21.2MB
    u16* xT  = (u16*)d_ws;
    u16* wbf = xT  + (size_t)4 * NN * CC;
    u16* qTw = wbf + (size_t)384 * CC;
    u16* kTw = qTw + (size_t)4 * NN * CQ;
    u16* vw  = kTw + (size_t)4 * NN * CQ;
    u16* Op0 = xT;                 // xT dead after qkv
    float* lws = (float*)wbf;      // wbf dead after qkv

    prep<<<1120, 256, 0, stream>>>(x, Wq, Wk, Wv, xT, wbf);
    qkv<<<512, 512, 0, stream>>>(xT, wbf, bq, bk, bv, qTw, kTw, vw);
    flash_attn<<<512, 512, 0, stream>>>(qTw, kTw, vw, Op0, out, lws);
    combine<<<4096, 256, 0, stream>>>(x, Op0, lws, gamma, out);
}

// Round 9
// 179.181 us; speedup vs baseline: 2.7165x; 1.0302x over previous
//
#include <hip/hip_runtime.h>
#include <hip/hip_bf16.h>

typedef unsigned short u16;
typedef unsigned int u32;
typedef float f32x4 __attribute__((ext_vector_type(4)));
typedef short s16x8 __attribute__((ext_vector_type(8)));

#define MFMA16(a, b, c) __builtin_amdgcn_mfma_f32_16x16x32_bf16(a, b, c, 0, 0, 0)

#define NN 4096
#define CC 256
#define CQ 64

__device__ __forceinline__ u16 f2bf(float x) {
    union { float f; u32 u; } v; v.f = x;
    return (u16)((v.u + 0x7FFFu + ((v.u >> 16) & 1u)) >> 16);
}
__device__ __forceinline__ float bf2f(u16 u) {
    union { u32 u; float f; } v; v.u = ((u32)u) << 16;
    return v.f;
}
// async global->LDS, 16B/lane; dst = wave-uniform base + lane*16 (m104)
__device__ __forceinline__ void gll16(const void* g, void* l) {
    __builtin_amdgcn_global_load_lds(
        (const __attribute__((address_space(1))) void*)g,
        (__attribute__((address_space(3))) void*)l, 16, 0, 0);
}

// ---------------------------------------------------------------------------
// qkv v3 (fused, prep eliminated): 512 blocks x 512 thr. Per block (b, 32-n):
//  - X: load x f32 coalesced (1 float4/thr/cc), transpose+convert via 4
//    ds_write_b16 into swizzled Xs[32][64] (same layout as v2's DMA staging:
//    Xs[n*64 + ((c>>3 ^ (n&7))*8) + (c&7)] = X[c0+c][n0+n]).
//  - W: A-frags loaded DIRECTLY from global f32 (Wq/Wk/Wv, L2-resident) and
//    converted in-register: frag = W[row][c0+kk*32+quad*8 .. +8]. The 16-row
//    A-tiles are 16-aligned so they never cross the Wq/Wk/Wv boundaries.
// No xT, no wbf, no prep kernel. Epilogue (bias + qT/kT/v writes) unchanged.
// ---------------------------------------------------------------------------
__global__ __launch_bounds__(512, 4) void qkv(
    const float* __restrict__ x,
    const float* __restrict__ Wq, const float* __restrict__ Wk,
    const float* __restrict__ Wv,
    const float* __restrict__ bq, const float* __restrict__ bk,
    const float* __restrict__ bv,
    u16* __restrict__ qT, u16* __restrict__ kT, u16* __restrict__ v)
{
    __shared__ __align__(16) u16 Xs[32 * 64];   // 4 KB swizzled bf16

    const int bid = blockIdx.x;
    const int b = bid >> 7, n0 = (bid & 127) * 32;
    const int t = threadIdx.x, lane = t & 63, w = t >> 6;
    const int col = lane & 15, quad = lane >> 4;
    const int xrow = t >> 3, xseg = t & 7;     // X-transpose ids: c-row, n-seg

    f32x4 acc[3][2];
    for (int i = 0; i < 3; i++) { acc[i][0] = f32x4{0,0,0,0}; acc[i][1] = f32x4{0,0,0,0}; }

    for (int cc = 0; cc < 4; cc++) {
        const int c0 = cc * 64;
        // ---- X tile: global f32 -> swizzled bf16 Xs
        const float4 xv = *(const float4*)(
            x + ((size_t)(b * CC + c0 + xrow)) * NN + n0 + xseg * 4);
        __syncthreads();               // prior-cc readers of Xs done
        {
            const float xe[4] = {xv.x, xv.y, xv.z, xv.w};
            for (int i = 0; i < 4; i++) {
                const int n = xseg * 4 + i;
                Xs[n * 64 + (((xrow >> 3) ^ (n & 7)) * 8) + (xrow & 7)] = f2bf(xe[i]);
            }
        }
        __syncthreads();               // Xs ready
        // ---- MFMA: W A-frags direct from global f32
        for (int kk = 0; kk < 2; kk++) {
            s16x8 bx[2];
            for (int nt2 = 0; nt2 < 2; nt2++) {
                const int n = nt2 * 16 + col;
                bx[nt2] = *(const s16x8*)&Xs[n * 64 + (((kk * 4 + quad) ^ (n & 7)) * 8)];
            }
            for (int ot = 0; ot < 3; ot++) {
                const int row = w * 48 + ot * 16 + col;
                const float* wsrc = (row < 64)  ? (Wq + (size_t)row * CC)
                                  : (row < 128) ? (Wk + (size_t)(row - 64) * CC)
                                                : (Wv + (size_t)(row - 128) * CC);
                const float4 a0 = *(const float4*)(wsrc + c0 + kk * 32 + quad * 8);
                const float4 a1 = *(const float4*)(wsrc + c0 + kk * 32 + quad * 8 + 4);
                union { u16 h[8]; s16x8 v8; } ap;
                ap.h[0] = f2bf(a0.x); ap.h[1] = f2bf(a0.y);
                ap.h[2] = f2bf(a0.z); ap.h[3] = f2bf(a0.w);
                ap.h[4] = f2bf(a1.x); ap.h[5] = f2bf(a1.y);
                ap.h[6] = f2bf(a1.z); ap.h[7] = f2bf(a1.w);
                acc[ot][0] = MFMA16(ap.v8, bx[0], acc[ot][0]);
                acc[ot][1] = MFMA16(ap.v8, bx[1], acc[ot][1]);
            }
        }
    }
    for (int ot = 0; ot < 3; ot++) {
        const int og = w * 48 + ot * 16 + quad * 4;   // wave-uniform 16-aligned region
        for (int nt2 = 0; nt2 < 2; nt2++) {
            const int n = n0 + nt2 * 16 + col;
            if (og < 64) {
                union { u16 h[4]; uint2 d; } pk;
                for (int r = 0; r < 4; r++) pk.h[r] = f2bf(acc[ot][nt2][r] + bq[og + r]);
                *(uint2*)(qT + ((size_t)(b * NN + n)) * CQ + og) = pk.d;
            } else if (og < 128) {
                union { u16 h[4]; uint2 d; } pk;
                for (int r = 0; r < 4; r++) pk.h[r] = f2bf(acc[ot][nt2][r] + bk[og - 64 + r]);
                *(uint2*)(kT + ((size_t)(b * NN + n)) * CQ + (og - 64)) = pk.d;
            } else {
                for (int r = 0; r < 4; r++)
                    v[((size_t)(b * CC + og - 128 + r)) * NN + n] =
                        f2bf(acc[ot][nt2][r] + bv[og - 128 + r]);
            }
        }
    }
}

// ---------------------------------------------------------------------------
// flash_attn v5 (REVERTED to R1's measured-best 80.8us version, unchanged):
// 64-i tile, jh 2-way j-split, skewed 1-barrier pipeline, XOR-swizzled V/P
// (conflicts 98K), XCD pin. jh=0 -> bf16 partial Op0, jh=1 -> f32 into out.
// LDS u16: K0@0 K1@2048 | V0@4096 V1@12288 | P0@20480 P1@22528 = 49152 B.
// ---------------------------------------------------------------------------
__global__ __launch_bounds__(512, 4) void flash_attn(
    const u16* __restrict__ qT, const u16* __restrict__ kT,
    const u16* __restrict__ v,
    u16* __restrict__ Op0, float* __restrict__ Op1,
    float* __restrict__ lws)
{
    __shared__ __align__(16) u16 sm[24576];   // 49152 B
    __shared__ float ls[2][64];

    const int bid = blockIdx.x;
    const int p = bid & 7;                 // XCD pin: (b, jh) per XCD, K/V-half in L2
    const int b = p >> 1, jh = p & 1;
    const int n0 = (bid >> 3) * 64;
    const int jb = jh * 2048;
    const int t = threadIdx.x;
    const int lane = t & 63, wv = t >> 6;
    const int col = lane & 15, quad = lane >> 4;
    const int strip = wv & 3, jhi = wv >> 2;   // S-phase identity
    const int ih = wv >> 2, cq = wv & 3;       // PV-phase identity

    // per-lane read swizzle for V and P (rows are base+col, base%16==0)
    const int swz8 = (quad ^ ((col >> 1) & 3)) * 8;

    // Q A-frags for S (A[m=i]: row = n0 + strip*16 + col)
    s16x8 aq[2];
    {
        const u16* qp = qT + ((size_t)(b * NN + n0 + strip * 16 + col)) * CQ + quad * 8;
        aq[0] = *(const s16x8*)qp;
        aq[1] = *(const s16x8*)(qp + 32);
    }

    f32x4 o_[2][4];    // D[m=i (quad*4+r), n=c (col)]: [it2 strip][ct c-tile]
    for (int i = 0; i < 2; i++) for (int j = 0; j < 4; j++) o_[i][j] = f32x4{0,0,0,0};
    float lac[4] = {0.f, 0.f, 0.f, 0.f};

    // staging addresses (K: 256 chunks via waves 0-3; V: 1024 chunks, 2/thread)
    const int kg = wv * 64 + lane;             // valid for wv<4
    const int krow = kg >> 3;
    const u16* ksrc = kT + ((size_t)(b * NN + jb + krow)) * CQ + (((kg & 7) ^ (krow & 7)) * 8);
    const int kdo = kg * 8;
    const u16* vsrc[2];
    int vdo[2];
    for (int m = 0; m < 2; m++) {
        const int g = m * 512 + t;
        const int row = g >> 2;                // 4 chunks per 32-j row
        vdo[m] = g * 8;
        // pre-swizzled global source: LDS slot (row, ch) holds global chunk
        // ch ^ ((row>>1)&3); involution matches the read-side XOR.
        vsrc[m] = v + ((size_t)(b * CC + row)) * NN + jb
                    + (((g & 3) ^ ((row >> 1) & 3)) * 8);
    }

    auto issueK = [&](int jt, int kb) {
        if (wv < 4) gll16(ksrc + (size_t)jt * 32 * CQ, sm + kb * 2048 + kdo);
    };
    auto issueV = [&](int jt, int vb) {
        u16* base = sm + 4096 + vb * 8192;
        for (int m = 0; m < 2; m++)
            gll16(vsrc[m] + jt * 32, base + vdo[m]);
    };
    auto S_phase = [&](int kb, int pb) {
        const u16* Kb = sm + kb * 2048;
        u16* Pb = sm + 20480 + pb * 2048;
        f32x4 s = f32x4{0,0,0,0};
        for (int kk = 0; kk < 2; kk++) {
            const int jrow = jhi * 16 + col;
            const s16x8 bk_ = *(const s16x8*)
                &Kb[jrow * 64 + (((kk * 4 + quad) ^ (jrow & 7)) * 8)];
            s = MFMA16(aq[kk], bk_, s);
        }
        const int jch = jhi * 2 + (col >> 3);  // 16B chunk of this lane's j
        const int jin = col & 7;
        for (int r = 0; r < 4; r++) {
            const float pv = __expf(fminf(s[r], 60.f));
            lac[r] += pv;
            const int rrow = strip * 16 + quad * 4 + r;
            Pb[rrow * 32 + ((jch ^ ((quad * 2 + (r >> 1)) & 3)) * 8) + jin] = f2bf(pv);
        }
    };
    auto PV_phase = [&](int pb, int vb) {
        const u16* Pb = sm + 20480 + pb * 2048;
        const u16* Vb = sm + 4096 + vb * 8192;
        s16x8 pa[2];
        for (int it2 = 0; it2 < 2; it2++)
            pa[it2] = *(const s16x8*)&Pb[((ih * 2 + it2) * 16 + col) * 32 + swz8];
        for (int ct = 0; ct < 4; ct++) {
            const int c = cq * 64 + ct * 16 + col;
            const s16x8 bv_ = *(const s16x8*)&Vb[c * 32 + swz8];
            o_[0][ct] = MFMA16(pa[0], bv_, o_[0][ct]);
            o_[1][ct] = MFMA16(pa[1], bv_, o_[1][ct]);
        }
    };

    // skewed 1-barrier pipeline (v2 schedule at half tile)
    issueK(0, 0);
    issueV(0, 0);
    issueK(1, 1);
    __syncthreads();
    S_phase(0, 0);

    int vcur = 0, pcur = 0;
    for (int m = 0; m < 64; m++) {
        __syncthreads();      // drains prior-iter DMAs; P[pcur] visible
        issueV((m + 1 < 64) ? m + 1 : 63, vcur ^ 1);
        issueK((m + 2 < 64) ? m + 2 : 63, m & 1);
        PV_phase(pcur, vcur);
        if (m < 63) S_phase((m + 1) & 1, pcur ^ 1);
        vcur ^= 1; pcur ^= 1;
    }

    // ---- l: reduce over this wave's 16 j-cols, publish per jhi half
    for (int r = 0; r < 4; r++) {
        float lv = lac[r];
        lv += __shfl_xor(lv, 1, 64);
        lv += __shfl_xor(lv, 2, 64);
        lv += __shfl_xor(lv, 4, 64);
        lv += __shfl_xor(lv, 8, 64);
        lac[r] = lv;
    }
    if (col == 0)
        for (int r = 0; r < 4; r++)
            ls[jhi][strip * 16 + quad * 4 + r] = lac[r];
    __syncthreads();   // drains trailing DMAs before sm reuse; ls visible
    if (t < 64)
        lws[(size_t)jh * 4 * NN + (size_t)b * NN + n0 + t] = ls[0][t] + ls[1][t];

    // ---- epilogue: transpose O through LDS in 2 rounds of 128 c
    float* Tf = (float*)sm;    // [128][68] f32 (34.8KB)
    u16*  Tu = sm;             // [128][136] u16
    for (int rd = 0; rd < 2; rd++) {
        if ((cq >> 1) == rd) {
            const int cl = (cq & 1) * 64;
            for (int it2 = 0; it2 < 2; it2++) {
                const int ib = (ih * 2 + it2) * 16 + quad * 4;
                for (int ct = 0; ct < 4; ct++) {
                    const int c = cl + ct * 16 + col;
                    if (jh == 0) {
                        union { u16 h[4]; uint2 d; } pk;
                        for (int r = 0; r < 4; r++) pk.h[r] = f2bf(o_[it2][ct][r]);
                        *(uint2*)&Tu[c * 136 + ib] = pk.d;
                    } else {
                        *(float2*)&Tf[c * 68 + ib] = float2{o_[it2][ct][0], o_[it2][ct][1]};
                        *(float2*)&Tf[c * 68 + ib + 2] = float2{o_[it2][ct][2], o_[it2][ct][3]};
                    }
                }
            }
        }
        __syncthreads();
        const int cl = t >> 2, i0 = (t & 3) * 16;
        const int c = rd * 128 + cl;
        if (jh == 0) {
            u16* dst = Op0 + ((size_t)(b * CC + c)) * NN + n0 + i0;
            *(uint4*)dst       = *(const uint4*)&Tu[cl * 136 + i0];
            *(uint4*)(dst + 8) = *(const uint4*)&Tu[cl * 136 + i0 + 8];
        } else {
            float* dst = Op1 + ((size_t)(b * CC + c)) * NN + n0 + i0;
            for (int k = 0; k < 4; k++)
                *(float4*)(dst + k * 4) = *(const float4*)&Tf[cl * 68 + i0 + k * 4];
        }
        __syncthreads();
    }
}

// ---------------------------------------------------------------------------
// combine: out = x + gamma * (O0 + O1) / (l0 + l1)   (in-place over d_out=O1)
// ---------------------------------------------------------------------------
__global__ __launch_bounds__(256) void combine(
    const float* __restrict__ x, const u16* __restrict__ Op0,
    const float* __restrict__ lws, const float* __restrict__ gamma,
    float* __restrict__ out)
{
    const size_t idx = ((size_t)blockIdx.x * 256 + threadIdx.x) * 4;
    const int b = (int)(idx >> 20);
    const int n = (int)(idx & (NN - 1));
    const float g = gamma[0];
    const float4 xv = *(const float4*)(x + idx);
    const float4 o1 = *(const float4*)(out + idx);
    union { uint2 d; u16 h[4]; } o0;
    o0.d = *(const uint2*)(Op0 + idx);
    const float4 l0 = *(const float4*)(lws + (size_t)b * NN + n);
    const float4 l1 = *(const float4*)(lws + (size_t)4 * NN + (size_t)b * NN + n);
    float4 r;
    r.x = xv.x + g * (bf2f(o0.h[0]) + o1.x) / (l0.x + l1.x);
    r.y = xv.y + g * (bf2f(o0.h[1]) + o1.y) / (l0.y + l1.y);
    r.z = xv.z + g * (bf2f(o0.h[2]) + o1.z) / (l0.z + l1.z);
    r.w = xv.w + g * (bf2f(o0.h[3]) + o1.w) / (l0.w + l1.w);
    *(float4*)(out + idx) = r;
}

// ---------------------------------------------------------------------------
extern "C" void kernel_launch(void* const* d_in, const int* in_sizes, int n_in,
                              void* d_out, int out_size, void* d_ws, size_t ws_size,
                              hipStream_t stream)
{
    const float* x     = (const float*)d_in[0];
    const float* Wq    = (const float*)d_in[1];
    const float* bq    = (const float*)d_in[2];
    const float* Wk    = (const float*)d_in[3];
    const float* bk    = (const float*)d_in[4];
    const float* Wv    = (const float*)d_in[5];
    const float* bv    = (const float*)d_in[6];
    const float* gamma = (const float*)d_in[7];
    float* out = (float*)d_out;

    // ws: Op0 8.4MB (u16) | lws 128KB (f32) | qT 2.1MB | kT 2.1MB | v 8.4MB
    //     = ~21.2MB (no xT/wbf — prep eliminated)
    u16* Op0   = (u16*)d_ws;
    float* lws = (float*)(Op0 + (size_t)4 * NN * CC);
    u16* qTw   = (u16*)(lws + (size_t)8 * NN);
    u16* kTw   = qTw + (size_t)4 * NN * CQ;
    u16* vw    = kTw + (size_t)4 * NN * CQ;

    qkv<<<512, 512, 0, stream>>>(x, Wq, Wk, Wv, bq, bk, bv, qTw, kTw, vw);
    flash_attn<<<512, 512, 0, stream>>>(qTw, kTw, vw, Op0, out, lws);
    combine<<<4096, 256, 0, stream>>>(x, Op0, lws, gamma, out);
}

// Round 10
// 169.880 us; speedup vs baseline: 2.8652x; 1.0547x over previous
//
#include <hip/hip_runtime.h>
#include <hip/hip_bf16.h>

typedef unsigned short u16;
typedef unsigned int u32;
typedef float f32x4 __attribute__((ext_vector_type(4)));
typedef short s16x8 __attribute__((ext_vector_type(8)));

#define MFMA16(a, b, c) __builtin_amdgcn_mfma_f32_16x16x32_bf16(a, b, c, 0, 0, 0)

#define NN 4096
#define CC 256
#define CQ 64

__device__ __forceinline__ u16 f2bf(float x) {
    union { float f; u32 u; } v; v.f = x;
    return (u16)((v.u + 0x7FFFu + ((v.u >> 16) & 1u)) >> 16);
}
__device__ __forceinline__ float bf2f(u16 u) {
    union { u32 u; float f; } v; v.u = ((u32)u) << 16;
    return v.f;
}
// async global->LDS, 16B/lane; dst = wave-uniform base + lane*16 (m104)
__device__ __forceinline__ void gll16(const void* g, void* l) {
    __builtin_amdgcn_global_load_lds(
        (const __attribute__((address_space(1))) void*)g,
        (__attribute__((address_space(3))) void*)l, 16, 0, 0);
}

// ---------------------------------------------------------------------------
// qkv v4 (fused, prep eliminated — W-path fixed vs R9):
// 512 blocks x 512 thr. Per block (b, 32-n):
//  - X: R9-verified self-transpose: 1 float4/thr/cc -> 4 ds_write_b16 into
//    swizzled Xs (same image as v2's DMA staging).
//  - W: per cc, each thread loads its 6 16B-chunks of W f32 (coalesced: the
//    XOR permutes chunks within a 256B row), converts to bf16 BEFORE the
//    barrier (6 x s16x8 in regs), then 6 ds_write_b128 reproduce v2's exact
//    swizzled Ws image. MFMA loop = v2's proven LDS-only code, untouched.
// Converts no longer serialize with MFMA (R9's mistake); traffic from L2.
// ---------------------------------------------------------------------------
__global__ __launch_bounds__(512, 4) void qkv(
    const float* __restrict__ x,
    const float* __restrict__ Wq, const float* __restrict__ Wk,
    const float* __restrict__ Wv,
    const float* __restrict__ bq, const float* __restrict__ bk,
    const float* __restrict__ bv,
    u16* __restrict__ qT, u16* __restrict__ kT, u16* __restrict__ v)
{
    __shared__ __align__(16) u16 sm[384 * 64 + 32 * 64];  // 53248 B
    u16* Ws = sm;             // [384][64] swizzled (v2 image)
    u16* Xs = sm + 384 * 64;  // [32][64] swizzled (v2 image)

    const int bid = blockIdx.x;
    const int b = bid >> 7, n0 = (bid & 127) * 32;
    const int t = threadIdx.x, lane = t & 63, w = t >> 6;
    const int col = lane & 15, quad = lane >> 4;
    const int xrow = t >> 3, xseg = t & 7;     // X-transpose ids: c-row, n-seg

    // per-thread W chunk sources (constant across cc up to +c0)
    const float* wsrcs[6];
    int wg[6];
    for (int m = 0; m < 6; m++) {
        const int g = m * 512 + t;
        const int row = g >> 3, ch = g & 7;
        const float* wsrc = (row < 64)  ? (Wq + (size_t)row * CC)
                          : (row < 128) ? (Wk + (size_t)(row - 64) * CC)
                                        : (Wv + (size_t)(row - 128) * CC);
        wsrcs[m] = wsrc + ((ch ^ (row & 7)) * 8);
        wg[m] = g;
    }

    f32x4 acc[3][2];
    for (int i = 0; i < 3; i++) { acc[i][0] = f32x4{0,0,0,0}; acc[i][1] = f32x4{0,0,0,0}; }

    for (int cc = 0; cc < 4; cc++) {
        const int c0 = cc * 64;
        // ---- global loads + early converts (overlap other waves' MFMA)
        const float4 xv4 = *(const float4*)(
            x + ((size_t)(b * CC + c0 + xrow)) * NN + n0 + xseg * 4);
        s16x8 wreg[6];
        for (int m = 0; m < 6; m++) {
            const float4 a0 = *(const float4*)(wsrcs[m] + c0);
            const float4 a1 = *(const float4*)(wsrcs[m] + c0 + 4);
            union { u16 h[8]; s16x8 v8; } pk;
            pk.h[0] = f2bf(a0.x); pk.h[1] = f2bf(a0.y);
            pk.h[2] = f2bf(a0.z); pk.h[3] = f2bf(a0.w);
            pk.h[4] = f2bf(a1.x); pk.h[5] = f2bf(a1.y);
            pk.h[6] = f2bf(a1.z); pk.h[7] = f2bf(a1.w);
            wreg[m] = pk.v8;
        }
        __syncthreads();               // prior-cc readers of Ws/Xs done
        {
            const float xe[4] = {xv4.x, xv4.y, xv4.z, xv4.w};
            for (int i = 0; i < 4; i++) {
                const int n = xseg * 4 + i;
                Xs[n * 64 + (((xrow >> 3) ^ (n & 7)) * 8) + (xrow & 7)] = f2bf(xe[i]);
            }
        }
        for (int m = 0; m < 6; m++)
            *(s16x8*)&Ws[wg[m] * 8] = wreg[m];
        __syncthreads();               // Ws/Xs ready
        // ---- MFMA loop: v2's proven LDS-only code
        for (int kk = 0; kk < 2; kk++) {
            s16x8 bx[2];
            for (int nt2 = 0; nt2 < 2; nt2++) {
                const int n = nt2 * 16 + col;
                bx[nt2] = *(const s16x8*)&Xs[n * 64 + (((kk * 4 + quad) ^ (n & 7)) * 8)];
            }
            for (int ot = 0; ot < 3; ot++) {
                const int row = w * 48 + ot * 16 + col;
                const s16x8 a = *(const s16x8*)&Ws[row * 64 + (((kk * 4 + quad) ^ (row & 7)) * 8)];
                acc[ot][0] = MFMA16(a, bx[0], acc[ot][0]);
                acc[ot][1] = MFMA16(a, bx[1], acc[ot][1]);
            }
        }
    }
    for (int ot = 0; ot < 3; ot++) {
        const int og = w * 48 + ot * 16 + quad * 4;   // wave-uniform 16-aligned region
        for (int nt2 = 0; nt2 < 2; nt2++) {
            const int n = n0 + nt2 * 16 + col;
            if (og < 64) {
                union { u16 h[4]; uint2 d; } pk;
                for (int r = 0; r < 4; r++) pk.h[r] = f2bf(acc[ot][nt2][r] + bq[og + r]);
                *(uint2*)(qT + ((size_t)(b * NN + n)) * CQ + og) = pk.d;
            } else if (og < 128) {
                union { u16 h[4]; uint2 d; } pk;
                for (int r = 0; r < 4; r++) pk.h[r] = f2bf(acc[ot][nt2][r] + bk[og - 64 + r]);
                *(uint2*)(kT + ((size_t)(b * NN + n)) * CQ + (og - 64)) = pk.d;
            } else {
                for (int r = 0; r < 4; r++)
                    v[((size_t)(b * CC + og - 128 + r)) * NN + n] =
                        f2bf(acc[ot][nt2][r] + bv[og - 128 + r]);
            }
        }
    }
}

// ---------------------------------------------------------------------------
// flash_attn v5 (R1's measured-best 80.8us version, unchanged):
// 64-i tile, jh 2-way j-split, skewed 1-barrier pipeline, XOR-swizzled V/P
// (conflicts 98K), XCD pin. jh=0 -> bf16 partial Op0, jh=1 -> f32 into out.
// LDS u16: K0@0 K1@2048 | V0@4096 V1@12288 | P0@20480 P1@22528 = 49152 B.
// ---------------------------------------------------------------------------
__global__ __launch_bounds__(512, 4) void flash_attn(
    const u16* __restrict__ qT, const u16* __restrict__ kT,
    const u16* __restrict__ v,
    u16* __restrict__ Op0, float* __restrict__ Op1,
    float* __restrict__ lws)
{
    __shared__ __align__(16) u16 sm[24576];   // 49152 B
    __shared__ float ls[2][64];

    const int bid = blockIdx.x;
    const int p = bid & 7;                 // XCD pin: (b, jh) per XCD, K/V-half in L2
    const int b = p >> 1, jh = p & 1;
    const int n0 = (bid >> 3) * 64;
    const int jb = jh * 2048;
    const int t = threadIdx.x;
    const int lane = t & 63, wv = t >> 6;
    const int col = lane & 15, quad = lane >> 4;
    const int strip = wv & 3, jhi = wv >> 2;   // S-phase identity
    const int ih = wv >> 2, cq = wv & 3;       // PV-phase identity

    // per-lane read swizzle for V and P (rows are base+col, base%16==0)
    const int swz8 = (quad ^ ((col >> 1) & 3)) * 8;

    // Q A-frags for S (A[m=i]: row = n0 + strip*16 + col)
    s16x8 aq[2];
    {
        const u16* qp = qT + ((size_t)(b * NN + n0 + strip * 16 + col)) * CQ + quad * 8;
        aq[0] = *(const s16x8*)qp;
        aq[1] = *(const s16x8*)(qp + 32);
    }

    f32x4 o_[2][4];    // D[m=i (quad*4+r), n=c (col)]: [it2 strip][ct c-tile]
    for (int i = 0; i < 2; i++) for (int j = 0; j < 4; j++) o_[i][j] = f32x4{0,0,0,0};
    float lac[4] = {0.f, 0.f, 0.f, 0.f};

    // staging addresses (K: 256 chunks via waves 0-3; V: 1024 chunks, 2/thread)
    const int kg = wv * 64 + lane;             // valid for wv<4
    const int krow = kg >> 3;
    const u16* ksrc = kT + ((size_t)(b * NN + jb + krow)) * CQ + (((kg & 7) ^ (krow & 7)) * 8);
    const int kdo = kg * 8;
    const u16* vsrc[2];
    int vdo[2];
    for (int m = 0; m < 2; m++) {
        const int g = m * 512 + t;
        const int row = g >> 2;                // 4 chunks per 32-j row
        vdo[m] = g * 8;
        // pre-swizzled global source: LDS slot (row, ch) holds global chunk
        // ch ^ ((row>>1)&3); involution matches the read-side XOR.
        vsrc[m] = v + ((size_t)(b * CC + row)) * NN + jb
                    + (((g & 3) ^ ((row >> 1) & 3)) * 8);
    }

    auto issueK = [&](int jt, int kb) {
        if (wv < 4) gll16(ksrc + (size_t)jt * 32 * CQ, sm + kb * 2048 + kdo);
    };
    auto issueV = [&](int jt, int vb) {
        u16* base = sm + 4096 + vb * 8192;
        for (int m = 0; m < 2; m++)
            gll16(vsrc[m] + jt * 32, base + vdo[m]);
    };
    auto S_phase = [&](int kb, int pb) {
        const u16* Kb = sm + kb * 2048;
        u16* Pb = sm + 20480 + pb * 2048;
        f32x4 s = f32x4{0,0,0,0};
        for (int kk = 0; kk < 2; kk++) {
            const int jrow = jhi * 16 + col;
            const s16x8 bk_ = *(const s16x8*)
                &Kb[jrow * 64 + (((kk * 4 + quad) ^ (jrow & 7)) * 8)];
            s = MFMA16(aq[kk], bk_, s);
        }
        const int jch = jhi * 2 + (col >> 3);  // 16B chunk of this lane's j
        const int jin = col & 7;
        for (int r = 0; r < 4; r++) {
            const float pv = __expf(fminf(s[r], 60.f));
            lac[r] += pv;
            const int rrow = strip * 16 + quad * 4 + r;
            Pb[rrow * 32 + ((jch ^ ((quad * 2 + (r >> 1)) & 3)) * 8) + jin] = f2bf(pv);
        }
    };
    auto PV_phase = [&](int pb, int vb) {
        const u16* Pb = sm + 20480 + pb * 2048;
        const u16* Vb = sm + 4096 + vb * 8192;
        s16x8 pa[2];
        for (int it2 = 0; it2 < 2; it2++)
            pa[it2] = *(const s16x8*)&Pb[((ih * 2 + it2) * 16 + col) * 32 + swz8];
        for (int ct = 0; ct < 4; ct++) {
            const int c = cq * 64 + ct * 16 + col;
            const s16x8 bv_ = *(const s16x8*)&Vb[c * 32 + swz8];
            o_[0][ct] = MFMA16(pa[0], bv_, o_[0][ct]);
            o_[1][ct] = MFMA16(pa[1], bv_, o_[1][ct]);
        }
    };

    // skewed 1-barrier pipeline (v2 schedule at half tile)
    issueK(0, 0);
    issueV(0, 0);
    issueK(1, 1);
    __syncthreads();
    S_phase(0, 0);

    int vcur = 0, pcur = 0;
    for (int m = 0; m < 64; m++) {
        __syncthreads();      // drains prior-iter DMAs; P[pcur] visible
        issueV((m + 1 < 64) ? m + 1 : 63, vcur ^ 1);
        issueK((m + 2 < 64) ? m + 2 : 63, m & 1);
        PV_phase(pcur, vcur);
        if (m < 63) S_phase((m + 1) & 1, pcur ^ 1);
        vcur ^= 1; pcur ^= 1;
    }

    // ---- l: reduce over this wave's 16 j-cols, publish per jhi half
    for (int r = 0; r < 4; r++) {
        float lv = lac[r];
        lv += __shfl_xor(lv, 1, 64);
        lv += __shfl_xor(lv, 2, 64);
        lv += __shfl_xor(lv, 4, 64);
        lv += __shfl_xor(lv, 8, 64);
        lac[r] = lv;
    }
    if (col == 0)
        for (int r = 0; r < 4; r++)
            ls[jhi][strip * 16 + quad * 4 + r] = lac[r];
    __syncthreads();   // drains trailing DMAs before sm reuse; ls visible
    if (t < 64)
        lws[(size_t)jh * 4 * NN + (size_t)b * NN + n0 + t] = ls[0][t] + ls[1][t];

    // ---- epilogue: transpose O through LDS in 2 rounds of 128 c
    float* Tf = (float*)sm;    // [128][68] f32 (34.8KB)
    u16*  Tu = sm;             // [128][136] u16
    for (int rd = 0; rd < 2; rd++) {
        if ((cq >> 1) == rd) {
            const int cl = (cq & 1) * 64;
            for (int it2 = 0; it2 < 2; it2++) {
                const int ib = (ih * 2 + it2) * 16 + quad * 4;
                for (int ct = 0; ct < 4; ct++) {
                    const int c = cl + ct * 16 + col;
                    if (jh == 0) {
                        union { u16 h[4]; uint2 d; } pk;
                        for (int r = 0; r < 4; r++) pk.h[r] = f2bf(o_[it2][ct][r]);
                        *(uint2*)&Tu[c * 136 + ib] = pk.d;
                    } else {
                        *(float2*)&Tf[c * 68 + ib] = float2{o_[it2][ct][0], o_[it2][ct][1]};
                        *(float2*)&Tf[c * 68 + ib + 2] = float2{o_[it2][ct][2], o_[it2][ct][3]};
                    }
                }
            }
        }
        __syncthreads();
        const int cl = t >> 2, i0 = (t & 3) * 16;
        const int c = rd * 128 + cl;
        if (jh == 0) {
            u16* dst = Op0 + ((size_t)(b * CC + c)) * NN + n0 + i0;
            *(uint4*)dst       = *(const uint4*)&Tu[cl * 136 + i0];
            *(uint4*)(dst + 8) = *(const uint4*)&Tu[cl * 136 + i0 + 8];
        } else {
            float* dst = Op1 + ((size_t)(b * CC + c)) * NN + n0 + i0;
            for (int k = 0; k < 4; k++)
                *(float4*)(dst + k * 4) = *(const float4*)&Tf[cl * 68 + i0 + k * 4];
        }
        __syncthreads();
    }
}

// ---------------------------------------------------------------------------
// combine: out = x + gamma * (O0 + O1) / (l0 + l1)   (in-place over d_out=O1)
// ---------------------------------------------------------------------------
__global__ __launch_bounds__(256) void combine(
    const float* __restrict__ x, const u16* __restrict__ Op0,
    const float* __restrict__ lws, const float* __restrict__ gamma,
    float* __restrict__ out)
{
    const size_t idx = ((size_t)blockIdx.x * 256 + threadIdx.x) * 4;
    const int b = (int)(idx >> 20);
    const int n = (int)(idx & (NN - 1));
    const float g = gamma[0];
    const float4 xv = *(const float4*)(x + idx);
    const float4 o1 = *(const float4*)(out + idx);
    union { uint2 d; u16 h[4]; } o0;
    o0.d = *(const uint2*)(Op0 + idx);
    const float4 l0 = *(const float4*)(lws + (size_t)b * NN + n);
    const float4 l1 = *(const float4*)(lws + (size_t)4 * NN + (size_t)b * NN + n);
    float4 r;
    r.x = xv.x + g * (bf2f(o0.h[0]) + o1.x) / (l0.x + l1.x);
    r.y = xv.y + g * (bf2f(o0.h[1]) + o1.y) / (l0.y + l1.y);
    r.z = xv.z + g * (bf2f(o0.h[2]) + o1.z) / (l0.z + l1.z);
    r.w = xv.w + g * (bf2f(o0.h[3]) + o1.w) / (l0.w + l1.w);
    *(float4*)(out + idx) = r;
}

// ---------------------------------------------------------------------------
extern "C" void kernel_launch(void* const* d_in, const int* in_sizes, int n_in,
                              void* d_out, int out_size, void* d_ws, size_t ws_size,
                              hipStream_t stream)
{
    const float* x     = (const float*)d_in[0];
    const float* Wq    = (const float*)d_in[1];
    const float* bq    = (const float*)d_in[2];
    const float* Wk    = (const float*)d_in[3];
    const float* bk    = (const float*)d_in[4];
    const float* Wv    = (const float*)d_in[5];
    const float* bv    = (const float*)d_in[6];
    const float* gamma = (const float*)d_in[7];
    float* out = (float*)d_out;

    // ws: Op0 8.4MB (u16) | lws 128KB (f32) | qT 2.1MB | kT 2.1MB | v 8.4MB
    //     = ~21.2MB (no xT/wbf — prep eliminated)
    u16* Op0   = (u16*)d_ws;
    float* lws = (float*)(Op0 + (size_t)4 * NN * CC);
    u16* qTw   = (u16*)(lws + (size_t)8 * NN);
    u16* kTw   = qTw + (size_t)4 * NN * CQ;
    u16* vw    = kTw + (size_t)4 * NN * CQ;

    qkv<<<512, 512, 0, stream>>>(x, Wq, Wk, Wv, bq, bk, bv, qTw, kTw, vw);
    flash_attn<<<512, 512, 0, stream>>>(qTw, kTw, vw, Op0, out, lws);
    combine<<<4096, 256, 0, stream>>>(x, Op0, lws, gamma, out);
}

// Round 11
// 168.289 us; speedup vs baseline: 2.8923x; 1.0095x over previous
//
#include <hip/hip_runtime.h>
#include <hip/hip_bf16.h>

typedef unsigned short u16;
typedef unsigned int u32;
typedef float f32x4 __attribute__((ext_vector_type(4)));
typedef short s16x8 __attribute__((ext_vector_type(8)));

#define MFMA16(a, b, c) __builtin_amdgcn_mfma_f32_16x16x32_bf16(a, b, c, 0, 0, 0)

#define NN 4096
#define CC 256
#define CQ 64

__device__ __forceinline__ u16 f2bf(float x) {
    union { float f; u32 u; } v; v.f = x;
    return (u16)((v.u + 0x7FFFu + ((v.u >> 16) & 1u)) >> 16);
}
__device__ __forceinline__ float bf2f(u16 u) {
    union { u32 u; float f; } v; v.u = ((u32)u) << 16;
    return v.f;
}
// async global->LDS, 16B/lane; dst = wave-uniform base + lane*16 (m104)
__device__ __forceinline__ void gll16(const void* g, void* l) {
    __builtin_amdgcn_global_load_lds(
        (const __attribute__((address_space(1))) void*)g,
        (__attribute__((address_space(3))) void*)l, 16, 0, 0);
}

// ---------------------------------------------------------------------------
// SESSION-BEST CONFIGURATION (R1, 167.4 us measured). Selected after 8
// structural attacks on flash_attn all regressed or were neutral:
//   - V/P XOR-swizzle (R0->R1): +3.0 us  [kept: conflicts 6.39M -> 98K]
//   - 128-i tile / LDS-volume (R2): -3.6 us [reverted]
//   - counted-vmcnt 3-deep (R3): -10 us [reverted]
//   - cross-block fused combine (R4): catastrophic [reverted]
//   - i-split no-combine (R6): -39 us [reverted]
//   - swapped-operand S (R8): -19 us [reverted]
//   - prep-fused qkv (R9/R10): neutral (non-flash is a harness floor)
// flash is dependency-bound (no pipe >82%, occupancy capped by LDS+grid);
// non-flash ~85 us is insensitive to kernel count/traffic.
// ---------------------------------------------------------------------------

// ---------------------------------------------------------------------------
// prep: blocks 0..1023: x[b][c][n] f32 -> xT[b][n][c] bf16 (LDS transpose)
//       blocks 1024..1119: Wq|Wk|Wv f32 -> wbf[384][256] bf16
// ---------------------------------------------------------------------------
__global__ __launch_bounds__(256) void prep(
    const float* __restrict__ x, const float* __restrict__ Wq,
    const float* __restrict__ Wk, const float* __restrict__ Wv,
    u16* __restrict__ xT, u16* __restrict__ wbf)
{
    const int bid = blockIdx.x, t = threadIdx.x;
    if (bid < 1024) {
        __shared__ float tile[64 * 65];
        const int b = bid >> 8, ctile = (bid >> 6) & 3, ntile = bid & 63;
        const int c0 = ctile * 64, n0 = ntile * 64;
        const int cw = t >> 4, nj = (t & 15) * 4;
        for (int it = 0; it < 4; it++) {
            const int ci = it * 16 + cw;
            const float4 v4 = *(const float4*)(x + ((size_t)(b * CC + c0 + ci)) * NN + n0 + nj);
            tile[(nj + 0) * 65 + ci] = v4.x;
            tile[(nj + 1) * 65 + ci] = v4.y;
            tile[(nj + 2) * 65 + ci] = v4.z;
            tile[(nj + 3) * 65 + ci] = v4.w;
        }
        __syncthreads();
        const int r = t >> 2, c16 = (t & 3) * 16;
        union { u16 h[16]; uint4 q[2]; } pk;
        for (int j = 0; j < 16; j++) pk.h[j] = f2bf(tile[r * 65 + c16 + j]);
        u16* dst = xT + ((size_t)(b * NN + n0 + r)) * CC + c0 + c16;
        *(uint4*)dst = pk.q[0];
        *(uint4*)(dst + 8) = pk.q[1];
    } else {
        const int flat = (bid - 1024) * 1024 + t * 4;
        const int o = flat >> 8, c = flat & 255;
        const float* src = (o < 64)  ? (Wq + (size_t)o * CC + c)
                         : (o < 128) ? (Wk + (size_t)(o - 64) * CC + c)
                                     : (Wv + (size_t)(o - 128) * CC + c);
        const float4 v4 = *(const float4*)src;
        union { u16 h[4]; uint2 d; } pk;
        pk.h[0] = f2bf(v4.x); pk.h[1] = f2bf(v4.y);
        pk.h[2] = f2bf(v4.z); pk.h[3] = f2bf(v4.w);
        *(uint2*)(wbf + (size_t)o * CC + c) = pk.d;
    }
}

// ---------------------------------------------------------------------------
// qkv v2: 512 blocks (2/CU) x 512 thr (8 waves; 16 waves/CU). n-tile 32.
// Each wave: 48 W-rows (3 o-tiles) x 32 n. Async swizzled staging.
// ---------------------------------------------------------------------------
__global__ __launch_bounds__(512, 4) void qkv(
    const u16* __restrict__ xT, const u16* __restrict__ wbf,
    const float* __restrict__ bq, const float* __restrict__ bk,
    const float* __restrict__ bv,
    u16* __restrict__ qT, u16* __restrict__ kT, u16* __restrict__ v)
{
    __shared__ __align__(16) u16 sm[384 * 64 + 32 * 64];  // 53248 B
    u16* Ws = sm;             // [384][64] swizzled
    u16* Xs = sm + 384 * 64;  // [32][64] swizzled

    const int bid = blockIdx.x;
    const int b = bid >> 7, n0 = (bid & 127) * 32;
    const int t = threadIdx.x, lane = t & 63, w = t >> 6;
    const int col = lane & 15, quad = lane >> 4;

    f32x4 acc[3][2];
    for (int i = 0; i < 3; i++) { acc[i][0] = f32x4{0,0,0,0}; acc[i][1] = f32x4{0,0,0,0}; }

    for (int cc = 0; cc < 4; cc++) {
        const int c0 = cc * 64;
        for (int m = 0; m < 6; m++) {
            const int g = m * 512 + t;
            const int row = g >> 3, ch = g & 7;
            gll16(wbf + (size_t)row * CC + c0 + ((ch ^ (row & 7)) * 8), Ws + g * 8);
        }
        if (w < 4) {
            const int g = w * 64 + lane;
            const int n = g >> 3, ch = g & 7;
            gll16(xT + ((size_t)(b * NN + n0 + n)) * CC + c0 + ((ch ^ (n & 7)) * 8),
                  Xs + g * 8);
        }
        __syncthreads();
        for (int kk = 0; kk < 2; kk++) {
            s16x8 bx[2];
            for (int nt2 = 0; nt2 < 2; nt2++) {
                const int n = nt2 * 16 + col;
                bx[nt2] = *(const s16x8*)&Xs[n * 64 + (((kk * 4 + quad) ^ (n & 7)) * 8)];
            }
            for (int ot = 0; ot < 3; ot++) {
                const int row = w * 48 + ot * 16 + col;
                const s16x8 a = *(const s16x8*)&Ws[row * 64 + (((kk * 4 + quad) ^ (row & 7)) * 8)];
                acc[ot][0] = MFMA16(a, bx[0], acc[ot][0]);
                acc[ot][1] = MFMA16(a, bx[1], acc[ot][1]);
            }
        }
        __syncthreads();
    }
    for (int ot = 0; ot < 3; ot++) {
        const int og = w * 48 + ot * 16 + quad * 4;   // wave-uniform 16-aligned region
        for (int nt2 = 0; nt2 < 2; nt2++) {
            const int n = n0 + nt2 * 16 + col;
            if (og < 64) {
                union { u16 h[4]; uint2 d; } pk;
                for (int r = 0; r < 4; r++) pk.h[r] = f2bf(acc[ot][nt2][r] + bq[og + r]);
                *(uint2*)(qT + ((size_t)(b * NN + n)) * CQ + og) = pk.d;
            } else if (og < 128) {
                union { u16 h[4]; uint2 d; } pk;
                for (int r = 0; r < 4; r++) pk.h[r] = f2bf(acc[ot][nt2][r] + bk[og - 64 + r]);
                *(uint2*)(kT + ((size_t)(b * NN + n)) * CQ + (og - 64)) = pk.d;
            } else {
                for (int r = 0; r < 4; r++)
                    v[((size_t)(b * CC + og - 128 + r)) * NN + n] =
                        f2bf(acc[ot][nt2][r] + bv[og - 128 + r]);
            }
        }
    }
}

// ---------------------------------------------------------------------------
// flash_attn v5 (measured best: 80.8us): 64-i tile, jh 2-way j-split,
// skewed 1-barrier pipeline, XOR-swizzled V/P (conflicts 98K), XCD pin.
// jh=0 -> bf16 partial Op0, jh=1 -> f32 partial into out.
// LDS u16: K0@0 K1@2048 | V0@4096 V1@12288 | P0@20480 P1@22528 = 49152 B.
// ---------------------------------------------------------------------------
__global__ __launch_bounds__(512, 4) void flash_attn(
    const u16* __restrict__ qT, const u16* __restrict__ kT,
    const u16* __restrict__ v,
    u16* __restrict__ Op0, float* __restrict__ Op1,
    float* __restrict__ lws)
{
    __shared__ __align__(16) u16 sm[24576];   // 49152 B
    __shared__ float ls[2][64];

    const int bid = blockIdx.x;
    const int p = bid & 7;                 // XCD pin: (b, jh) per XCD, K/V-half in L2
    const int b = p >> 1, jh = p & 1;
    const int n0 = (bid >> 3) * 64;
    const int jb = jh * 2048;
    const int t = threadIdx.x;
    const int lane = t & 63, wv = t >> 6;
    const int col = lane & 15, quad = lane >> 4;
    const int strip = wv & 3, jhi = wv >> 2;   // S-phase identity
    const int ih = wv >> 2, cq = wv & 3;       // PV-phase identity

    // per-lane read swizzle for V and P (rows are base+col, base%16==0)
    const int swz8 = (quad ^ ((col >> 1) & 3)) * 8;

    // Q A-frags for S (A[m=i]: row = n0 + strip*16 + col)
    s16x8 aq[2];
    {
        const u16* qp = qT + ((size_t)(b * NN + n0 + strip * 16 + col)) * CQ + quad * 8;
        aq[0] = *(const s16x8*)qp;
        aq[1] = *(const s16x8*)(qp + 32);
    }

    f32x4 o_[2][4];    // D[m=i (quad*4+r), n=c (col)]: [it2 strip][ct c-tile]
    for (int i = 0; i < 2; i++) for (int j = 0; j < 4; j++) o_[i][j] = f32x4{0,0,0,0};
    float lac[4] = {0.f, 0.f, 0.f, 0.f};

    // staging addresses (K: 256 chunks via waves 0-3; V: 1024 chunks, 2/thread)
    const int kg = wv * 64 + lane;             // valid for wv<4
    const int krow = kg >> 3;
    const u16* ksrc = kT + ((size_t)(b * NN + jb + krow)) * CQ + (((kg & 7) ^ (krow & 7)) * 8);
    const int kdo = kg * 8;
    const u16* vsrc[2];
    int vdo[2];
    for (int m = 0; m < 2; m++) {
        const int g = m * 512 + t;
        const int row = g >> 2;                // 4 chunks per 32-j row
        vdo[m] = g * 8;
        // pre-swizzled global source: LDS slot (row, ch) holds global chunk
        // ch ^ ((row>>1)&3); involution matches the read-side XOR.
        vsrc[m] = v + ((size_t)(b * CC + row)) * NN + jb
                    + (((g & 3) ^ ((row >> 1) & 3)) * 8);
    }

    auto issueK = [&](int jt, int kb) {
        if (wv < 4) gll16(ksrc + (size_t)jt * 32 * CQ, sm + kb * 2048 + kdo);
    };
    auto issueV = [&](int jt, int vb) {
        u16* base = sm + 4096 + vb * 8192;
        for (int m = 0; m < 2; m++)
            gll16(vsrc[m] + jt * 32, base + vdo[m]);
    };
    auto S_phase = [&](int kb, int pb) {
        const u16* Kb = sm + kb * 2048;
        u16* Pb = sm + 20480 + pb * 2048;
        f32x4 s = f32x4{0,0,0,0};
        for (int kk = 0; kk < 2; kk++) {
            const int jrow = jhi * 16 + col;
            const s16x8 bk_ = *(const s16x8*)
                &Kb[jrow * 64 + (((kk * 4 + quad) ^ (jrow & 7)) * 8)];
            s = MFMA16(aq[kk], bk_, s);
        }
        const int jch = jhi * 2 + (col >> 3);  // 16B chunk of this lane's j
        const int jin = col & 7;
        for (int r = 0; r < 4; r++) {
            const float pv = __expf(fminf(s[r], 60.f));
            lac[r] += pv;
            const int rrow = strip * 16 + quad * 4 + r;
            Pb[rrow * 32 + ((jch ^ ((quad * 2 + (r >> 1)) & 3)) * 8) + jin] = f2bf(pv);
        }
    };
    auto PV_phase = [&](int pb, int vb) {
        const u16* Pb = sm + 20480 + pb * 2048;
        const u16* Vb = sm + 4096 + vb * 8192;
        s16x8 pa[2];
        for (int it2 = 0; it2 < 2; it2++)
            pa[it2] = *(const s16x8*)&Pb[((ih * 2 + it2) * 16 + col) * 32 + swz8];
        for (int ct = 0; ct < 4; ct++) {
            const int c = cq * 64 + ct * 16 + col;
            const s16x8 bv_ = *(const s16x8*)&Vb[c * 32 + swz8];
            o_[0][ct] = MFMA16(pa[0], bv_, o_[0][ct]);
            o_[1][ct] = MFMA16(pa[1], bv_, o_[1][ct]);
        }
    };

    // skewed 1-barrier pipeline (v2 schedule at half tile)
    issueK(0, 0);
    issueV(0, 0);
    issueK(1, 1);
    __syncthreads();
    S_phase(0, 0);

    int vcur = 0, pcur = 0;
    for (int m = 0; m < 64; m++) {
        __syncthreads();      // drains prior-iter DMAs; P[pcur] visible
        issueV((m + 1 < 64) ? m + 1 : 63, vcur ^ 1);
        issueK((m + 2 < 64) ? m + 2 : 63, m & 1);
        PV_phase(pcur, vcur);
        if (m < 63) S_phase((m + 1) & 1, pcur ^ 1);
        vcur ^= 1; pcur ^= 1;
    }

    // ---- l: reduce over this wave's 16 j-cols, publish per jhi half
    for (int r = 0; r < 4; r++) {
        float lv = lac[r];
        lv += __shfl_xor(lv, 1, 64);
        lv += __shfl_xor(lv, 2, 64);
        lv += __shfl_xor(lv, 4, 64);
        lv += __shfl_xor(lv, 8, 64);
        lac[r] = lv;
    }
    if (col == 0)
        for (int r = 0; r < 4; r++)
            ls[jhi][strip * 16 + quad * 4 + r] = lac[r];
    __syncthreads();   // drains trailing DMAs before sm reuse; ls visible
    if (t < 64)
        lws[(size_t)jh * 4 * NN + (size_t)b * NN + n0 + t] = ls[0][t] + ls[1][t];

    // ---- epilogue: transpose O through LDS in 2 rounds of 128 c
    float* Tf = (float*)sm;    // [128][68] f32 (34.8KB)
    u16*  Tu = sm;             // [128][136] u16
    for (int rd = 0; rd < 2; rd++) {
        if ((cq >> 1) == rd) {
            const int cl = (cq & 1) * 64;
            for (int it2 = 0; it2 < 2; it2++) {
                const int ib = (ih * 2 + it2) * 16 + quad * 4;
                for (int ct = 0; ct < 4; ct++) {
                    const int c = cl + ct * 16 + col;
                    if (jh == 0) {
                        union { u16 h[4]; uint2 d; } pk;
                        for (int r = 0; r < 4; r++) pk.h[r] = f2bf(o_[it2][ct][r]);
                        *(uint2*)&Tu[c * 136 + ib] = pk.d;
                    } else {
                        *(float2*)&Tf[c * 68 + ib] = float2{o_[it2][ct][0], o_[it2][ct][1]};
                        *(float2*)&Tf[c * 68 + ib + 2] = float2{o_[it2][ct][2], o_[it2][ct][3]};
                    }
                }
            }
        }
        __syncthreads();
        const int cl = t >> 2, i0 = (t & 3) * 16;
        const int c = rd * 128 + cl;
        if (jh == 0) {
            u16* dst = Op0 + ((size_t)(b * CC + c)) * NN + n0 + i0;
            *(uint4*)dst       = *(const uint4*)&Tu[cl * 136 + i0];
            *(uint4*)(dst + 8) = *(const uint4*)&Tu[cl * 136 + i0 + 8];
        } else {
            float* dst = Op1 + ((size_t)(b * CC + c)) * NN + n0 + i0;
            for (int k = 0; k < 4; k++)
                *(float4*)(dst + k * 4) = *(const float4*)&Tf[cl * 68 + i0 + k * 4];
        }
        __syncthreads();
    }
}

// ---------------------------------------------------------------------------
// combine: out = x + gamma * (O0 + O1) / (l0 + l1)   (in-place over d_out=O1)
// ---------------------------------------------------------------------------
__global__ __launch_bounds__(256) void combine(
    const float* __restrict__ x, const u16* __restrict__ Op0,
    const float* __restrict__ lws, const float* __restrict__ gamma,
    float* __restrict__ out)
{
    const size_t idx = ((size_t)blockIdx.x * 256 + threadIdx.x) * 4;
    const int b = (int)(idx >> 20);
    const int n = (int)(idx & (NN - 1));
    const float g = gamma[0];
    const float4 xv = *(const float4*)(x + idx);
    const float4 o1 = *(const float4*)(out + idx);
    union { uint2 d; u16 h[4]; } o0;
    o0.d = *(const uint2*)(Op0 + idx);
    const float4 l0 = *(const float4*)(lws + (size_t)b * NN + n);
    const float4 l1 = *(const float4*)(lws + (size_t)4 * NN + (size_t)b * NN + n);
    float4 r;
    r.x = xv.x + g * (bf2f(o0.h[0]) + o1.x) / (l0.x + l1.x);
    r.y = xv.y + g * (bf2f(o0.h[1]) + o1.y) / (l0.y + l1.y);
    r.z = xv.z + g * (bf2f(o0.h[2]) + o1.z) / (l0.z + l1.z);
    r.w = xv.w + g * (bf2f(o0.h[3]) + o1.w) / (l0.w + l1.w);
    *(float4*)(out + idx) = r;
}

// ---------------------------------------------------------------------------
extern "C" void kernel_launch(void* const* d_in, const int* in_sizes, int n_in,
                              void* d_out, int out_size, void* d_ws, size_t ws_size,
                              hipStream_t stream)
{
    const float* x     = (const float*)d_in[0];
    const float* Wq    = (const float*)d_in[1];
    const float* bq    = (const float*)d_in[2];
    const float* Wk    = (const float*)d_in[3];
    const float* bk    = (const float*)d_in[4];
    const float* Wv    = (const float*)d_in[5];
    const float* bv    = (const float*)d_in[6];
    const float* gamma = (const float*)d_in[7];
    float* out = (float*)d_out;

    // ws (u16): xT 8.4MB (reused as Op0) | wbf 196KB (reused as lws 128KB)
    //           | qT 2.1MB | kT 2.1MB | v 8.4MB  — total ~21.2MB
    u16* xT  = (u16*)d_ws;
    u16* wbf = xT  + (size_t)4 * NN * CC;
    u16* qTw = wbf + (size_t)384 * CC;
    u16* kTw = qTw + (size_t)4 * NN * CQ;
    u16* vw  = kTw + (size_t)4 * NN * CQ;
    u16* Op0 = xT;                 // xT dead after qkv
    float* lws = (float*)wbf;      // wbf dead after qkv

    prep<<<1120, 256, 0, stream>>>(x, Wq, Wk, Wv, xT, wbf);
    qkv<<<512, 512, 0, stream>>>(xT, wbf, bq, bk, bv, qTw, kTw, vw);
    flash_attn<<<512, 512, 0, stream>>>(qTw, kTw, vw, Op0, out, lws);
    combine<<<4096, 256, 0, stream>>>(x, Op0, lws, gamma, out);
}